// Round 12
// baseline (228.680 us; speedup 1.0000x reference)
//
#include <hip/hip_runtime.h>
#include <hip/hip_bf16.h>
#include <stdint.h>

#define B_N 8
#define T_N 1024
#define C_N 768
#define M_N (B_N*T_N)   // 8192
#define NCH 32          // chunks along T
#define LCH (T_N/NCH)   // 32
#define BK32 32
#define KS  (C_N/BK32)  // 24 K-steps

typedef __attribute__((ext_vector_type(4))) float f32x4;
typedef __attribute__((ext_vector_type(8))) short s16x8;
typedef __attribute__((ext_vector_type(4))) unsigned short u16x4;

__device__ __forceinline__ unsigned short f2bf(float f){
  unsigned int u = __float_as_uint(f);
  u += 0x7FFFu + ((u >> 16) & 1u);   // round-to-nearest-even
  return (unsigned short)(u >> 16);
}
__device__ __forceinline__ float bf2f(unsigned short h){
  return __uint_as_float(((unsigned int)h) << 16);
}

// async 16B global -> LDS (wave-uniform LDS base + lane*16, per-lane global src)
__device__ __forceinline__ void async16(const unsigned short* g, unsigned short* l){
  __builtin_amdgcn_global_load_lds(
      (const __attribute__((address_space(1))) unsigned int*)g,
      (__attribute__((address_space(3))) unsigned int*)l, 16, 0, 0);
}

// ---------------------------------------------------------------------------
// Fused weight-prep + mix (one launch). Blocks [0,2304): weight prep;
// blocks [2304, 2304+6144): q_shift+mix.
// ---------------------------------------------------------------------------
__global__ __launch_bounds__(256) void prep_mix(
    const float* __restrict__ x,
    const float* __restrict__ Wk, const float* __restrict__ Wv,
    const float* __restrict__ Wr, const float* __restrict__ Wo,
    const int* __restrict__ perm,
    const float* __restrict__ mk, const float* __restrict__ mv, const float* __restrict__ mr,
    unsigned short* __restrict__ Wall, unsigned short* __restrict__ Wop,
    unsigned short* __restrict__ xk, unsigned short* __restrict__ xv,
    unsigned short* __restrict__ xr)
{
  if (blockIdx.x < 2304){
    int idx = blockIdx.x*256 + threadIdx.x;   // [0, C_N*C_N)
    int r = idx / C_N, c = idx - r*C_N;
    int pr = perm[r];
    Wall[idx]                     = f2bf(Wk[pr*C_N + c]);
    Wall[idx +   (size_t)C_N*C_N] = f2bf(Wv[pr*C_N + c]);
    Wall[idx + 2*(size_t)C_N*C_N] = f2bf(Wr[pr*C_N + c]);
    Wop[idx] = f2bf(Wo[r*C_N + perm[c]]);
    return;
  }
  int idx = (blockIdx.x - 2304)*256 + threadIdx.x;   // [0, M_N*C_N/4)
  int n  = idx / (C_N/4);
  int c4 = (idx - n*(C_N/4)) * 4;
  int t = n & (T_N-1);
  int h = t >> 5, w = t & 31;
  int grp = c4 / 192;
  int dh = (grp==2) ? -1 : (grp==3) ? 1 : 0;
  int dw = (grp==0) ? -1 : (grp==1) ? 1 : 0;
  int h2 = h + dh, w2 = w + dw;
  bool valid = ((unsigned)h2 < 32u) && ((unsigned)w2 < 32u);
  f32x4 xc = *(const f32x4*)(x + (size_t)n*C_N + c4);
  f32x4 xx = {0.f,0.f,0.f,0.f};
  if (valid) xx = *(const f32x4*)(x + (size_t)(n + dh*32 + dw)*C_N + c4);
  f32x4 vk = *(const f32x4*)(mk + c4);
  f32x4 vv = *(const f32x4*)(mv + c4);
  f32x4 vr = *(const f32x4*)(mr + c4);
  u16x4 ok, ov, orr;
  #pragma unroll
  for (int i=0;i<4;++i){
    float d = xc[i] - xx[i];
    ok[i]  = f2bf(xx[i] + vk[i]*d);
    ov[i]  = f2bf(xx[i] + vv[i]*d);
    orr[i] = f2bf(xx[i] + vr[i]*d);
  }
  *(u16x4*)(xk + (size_t)n*C_N + c4) = ok;
  *(u16x4*)(xv + (size_t)n*C_N + c4) = ov;
  *(u16x4*)(xr + (size_t)n*C_N + c4) = orr;
}

// ---------------------------------------------------------------------------
// Fused k/v/r GEMM: 128x128 tile, 4 waves, BK=32, DOUBLE-buffered LDS (32 KB
// total incl. epilogue union) -> 5 blocks/CU: all 1152 blocks resident in one
// round (no tail). 1-step counted-vmcnt prefetch; T2 granule swizzle;
// mb-fastest XCD mapping (L2-hot); two-pass coalesced bf16 epilogue.
// ---------------------------------------------------------------------------
__global__ __launch_bounds__(256, 5) void gemm_kvr(
    const unsigned short* __restrict__ xk, const unsigned short* __restrict__ xv,
    const unsigned short* __restrict__ xr,
    const unsigned short* __restrict__ Wall,
    unsigned short* __restrict__ kb, unsigned short* __restrict__ vb,
    unsigned short* __restrict__ srb)
{
  // 1152 blocks = 8 XCD chunks x 144; within chunk: mb fastest (8 mb / nb)
  int flat = blockIdx.y * gridDim.x + blockIdx.x;
  const int xcd = flat & 7, q = flat >> 3;       // q in [0,144)
  const int mb = xcd*8 + (q & 7);                // [0,64)
  const int nb = q >> 3;                         // [0,18)
  const int m0 = mb * 128;
  const int n0 = nb * 128;
  const int z  = nb / 6;
  const unsigned short* A = (z==0)? xk : (z==1)? xv : xr;

  __shared__ union {
    struct { unsigned short As[2][128*BK32]; unsigned short Bs[2][128*BK32]; } s;
    unsigned short ct[64*132];                   // padded half C-tile (16.9 KB)
  } u;
  const int tid = threadIdx.x;
  const int lane = tid & 63, wid = tid >> 6;
  const int wr = wid >> 1, wc = wid & 1;
  f32x4 acc[4][4];
  #pragma unroll
  for (int i=0;i<4;++i)
    #pragma unroll
    for (int j=0;j<4;++j) acc[i][j] = (f32x4){0.f,0.f,0.f,0.f};

  const int sgcol = ((lane & 3) ^ ((lane >> 3) & 3)) * 8;
  const int srow  = lane >> 2;                 // 0..15
  const int lr  = lane & 15;
  const int kh  = lane >> 4;                   // 0..3
  const int phys = (kh ^ ((lr >> 1) & 3)) * 8; // read-side granule offset (elems)

  auto stage = [&](int buf, int k0){
    #pragma unroll
    for (int i=0;i<2;++i){
      int rbase = i*64 + wid*16;
      async16(&A   [(size_t)(m0 + rbase + srow)*C_N + k0 + sgcol], &u.s.As[buf][rbase*BK32]);
      async16(&Wall[(size_t)(n0 + rbase + srow)*C_N + k0 + sgcol], &u.s.Bs[buf][rbase*BK32]);
    }
  };

  auto compute = [&](int buf){
    s16x8 af[4], bfr[4];
    #pragma unroll
    for (int mi=0;mi<4;++mi) af[mi]  = *(const s16x8*)&u.s.As[buf][(wr*64 + mi*16 + lr)*BK32 + phys];
    #pragma unroll
    for (int ni=0;ni<4;++ni) bfr[ni] = *(const s16x8*)&u.s.Bs[buf][(wc*64 + ni*16 + lr)*BK32 + phys];
    __builtin_amdgcn_s_setprio(1);
    #pragma unroll
    for (int mi=0;mi<4;++mi)
      #pragma unroll
      for (int ni=0;ni<4;++ni)
        acc[mi][ni] = __builtin_amdgcn_mfma_f32_16x16x32_bf16(af[mi], bfr[ni], acc[mi][ni], 0,0,0);
    __builtin_amdgcn_s_setprio(0);
  };

  stage(0, 0);
  #pragma unroll 1
  for (int t = 0; t < KS; ++t){
    if (t + 1 < KS){
      stage((t+1)&1, (t+1)*BK32);
      asm volatile("s_waitcnt vmcnt(4)" ::: "memory");  // tile t landed, t+1 in flight
    } else {
      asm volatile("s_waitcnt vmcnt(0)" ::: "memory");
    }
    __builtin_amdgcn_s_barrier();
    compute(t & 1);
    __builtin_amdgcn_s_barrier();                       // guard buffer reuse
  }

  // ---- two-pass coalesced epilogue via padded half-tile LDS ----
  unsigned short* dst = (z==0)? kb : (z==1)? vb : srb;
  const int colbase = n0 - z*C_N;
  const int lr4 = (lane>>4)*4, lc = lane & 15;
  #pragma unroll
  for (int p=0;p<2;++p){
    if (p) __builtin_amdgcn_s_barrier();
    if (wr == p){
      #pragma unroll
      for (int mi=0;mi<4;++mi){
        #pragma unroll
        for (int ni=0;ni<4;++ni){
          #pragma unroll
          for (int i=0;i<4;++i){
            int r  = mi*16 + lr4 + i;          // 0..63 local row
            int cc = wc*64 + ni*16 + lc;
            float val = acc[mi][ni][i];
            if (z==2) val = 1.f/(1.f + __expf(-val));
            u.ct[r*132 + cc] = f2bf(val);
          }
        }
      }
    }
    __builtin_amdgcn_s_barrier();
    #pragma unroll
    for (int qq=0;qq<4;++qq){
      int f = (qq*256 + tid)*8;                // flat elem in 64x128
      int r = f >> 7, cc = f & 127;
      s16x8 v8 = *(const s16x8*)&u.ct[r*132 + cc];
      *(s16x8*)&dst[(size_t)(m0 + p*64 + r)*C_N + colbase + cc] = v8;
    }
  }
}

// ---------------------------------------------------------------------------
// Final GEMM: out = zp (M x C, bf16) * Wop^T — same 32 KB dbuf structure,
// 5 blocks/CU, direct f32 epilogue (full-line stores).
// ---------------------------------------------------------------------------
__global__ __launch_bounds__(256, 5) void gemm_out(
    const unsigned short* __restrict__ A, const unsigned short* __restrict__ Bw,
    float* __restrict__ out)
{
  // 384 blocks = 8 x 48; mb fastest within chunk
  int flat = blockIdx.y * gridDim.x + blockIdx.x;
  const int xcd = flat & 7, q = flat >> 3;      // q in [0,48)
  const int mb = xcd*8 + (q & 7);               // [0,64)
  const int nb = q >> 3;                        // [0,6)
  const int m0 = mb*128, n0 = nb*128;
  __shared__ __align__(16) unsigned short As[2][128*BK32];
  __shared__ __align__(16) unsigned short Bs[2][128*BK32];
  const int tid = threadIdx.x;
  const int lane = tid & 63, wid = tid >> 6;
  const int wr = wid >> 1, wc = wid & 1;
  f32x4 acc[4][4];
  #pragma unroll
  for (int i=0;i<4;++i)
    #pragma unroll
    for (int j=0;j<4;++j) acc[i][j] = (f32x4){0.f,0.f,0.f,0.f};

  const int sgcol = ((lane & 3) ^ ((lane >> 3) & 3)) * 8;
  const int srow  = lane >> 2;
  const int lr  = lane & 15;
  const int kh  = lane >> 4;
  const int phys = (kh ^ ((lr >> 1) & 3)) * 8;

  auto stage = [&](int buf, int k0){
    #pragma unroll
    for (int i=0;i<2;++i){
      int rbase = i*64 + wid*16;
      async16(&A [(size_t)(m0 + rbase + srow)*C_N + k0 + sgcol], &As[buf][rbase*BK32]);
      async16(&Bw[(size_t)(n0 + rbase + srow)*C_N + k0 + sgcol], &Bs[buf][rbase*BK32]);
    }
  };

  auto compute = [&](int buf){
    s16x8 af[4], bfr[4];
    #pragma unroll
    for (int mi=0;mi<4;++mi) af[mi]  = *(const s16x8*)&As[buf][(wr*64 + mi*16 + lr)*BK32 + phys];
    #pragma unroll
    for (int ni=0;ni<4;++ni) bfr[ni] = *(const s16x8*)&Bs[buf][(wc*64 + ni*16 + lr)*BK32 + phys];
    __builtin_amdgcn_s_setprio(1);
    #pragma unroll
    for (int mi=0;mi<4;++mi)
      #pragma unroll
      for (int ni=0;ni<4;++ni)
        acc[mi][ni] = __builtin_amdgcn_mfma_f32_16x16x32_bf16(af[mi], bfr[ni], acc[mi][ni], 0,0,0);
    __builtin_amdgcn_s_setprio(0);
  };

  stage(0, 0);
  #pragma unroll 1
  for (int t = 0; t < KS; ++t){
    if (t + 1 < KS){
      stage((t+1)&1, (t+1)*BK32);
      asm volatile("s_waitcnt vmcnt(4)" ::: "memory");
    } else {
      asm volatile("s_waitcnt vmcnt(0)" ::: "memory");
    }
    __builtin_amdgcn_s_barrier();
    compute(t & 1);
    __builtin_amdgcn_s_barrier();
  }

  const int lr4 = (lane>>4)*4, lc = lane & 15;
  #pragma unroll
  for (int mi=0;mi<4;++mi)
    #pragma unroll
    for (int ni=0;ni<4;++ni)
      #pragma unroll
      for (int i=0;i<4;++i){
        int m = m0 + wr*64 + mi*16 + lr4 + i;
        int n = n0 + wc*64 + ni*16 + lc;
        out[(size_t)m*C_N + n] = acc[mi][ni][i];
      }
}

// ---------------------------------------------------------------------------
// WKV chunked scan — x4 vectorized along j (4 independent scan chains/thread,
// u16x4/f32x4 loads). Layout identical to round 3 (verified).
// ---------------------------------------------------------------------------
__global__ __launch_bounds__(256) void wkv_phase1(
    const unsigned short* __restrict__ kb, const unsigned short* __restrict__ vb,
    const float* __restrict__ decay,
    float* __restrict__ sa, float* __restrict__ sb, float* __restrict__ sp)
{
  int gid = blockIdx.x*256 + threadIdx.x;       // [0, NCH*B_N*C_N/4)
  int jq = gid % (C_N/4);
  int cb = gid / (C_N/4);
  int b = cb % B_N, c = cb / B_N;
  int j = jq*4;
  f32x4 dv = *(const f32x4*)(decay + j);
  float w[4];
  #pragma unroll
  for (int e=0;e<4;++e) w[e] = -__expf(dv[e] * (1.0f/T_N));
  f32x4 a = {0.f,0.f,0.f,0.f}, bbv = {0.f,0.f,0.f,0.f};
  f32x4 p = {-1e38f,-1e38f,-1e38f,-1e38f};
  size_t base = ((size_t)b*T_N + c*LCH)*C_N + j;
  #pragma unroll 2
  for (int t = 0; t < LCH; ++t){
    size_t o = base + (size_t)t*C_N;
    u16x4 k4 = *(const u16x4*)(kb + o);
    u16x4 v4 = *(const u16x4*)(vb + o);
    #pragma unroll
    for (int e=0;e<4;++e){
      float kt = bf2f(k4[e]), vt = bf2f(v4[e]);
      float pw = p[e] + w[e];
      float q2 = fmaxf(pw, kt);
      float e1 = __expf(pw - q2), e2 = __expf(kt - q2);
      a[e]   = e1*a[e]   + e2*vt;
      bbv[e] = e1*bbv[e] + e2;
      p[e]   = q2;
    }
  }
  size_t sg = (size_t)cb*C_N + j;
  *(f32x4*)(sa + sg) = a;
  *(f32x4*)(sb + sg) = bbv;
  *(f32x4*)(sp + sg) = p;
}

__global__ __launch_bounds__(256) void wkv_phase2(
    const float* __restrict__ decay,
    float* __restrict__ sa, float* __restrict__ sb, float* __restrict__ sp)
{
  int g = blockIdx.x*256 + threadIdx.x;   // [0, B_N*C_N)
  int j = g % C_N, b = g / C_N;
  float w = -__expf(decay[j] * (1.0f/T_N));
  float wL = w * (float)LCH;
  float a = 0.f, bb = 0.f, p = -1e38f;
  for (int c = 0; c < NCH; ++c){
    size_t idx = ((size_t)c*B_N + b)*C_N + j;
    float la = sa[idx], lb = sb[idx], lp = sp[idx];
    sa[idx] = a; sb[idx] = bb; sp[idx] = p;   // incoming state for chunk c
    float p1 = p + wL;
    float pn = fmaxf(p1, lp);
    float e1 = __expf(p1 - pn), e2 = __expf(lp - pn);
    a  = e1*a + e2*la;
    bb = e1*bb + e2*lb;
    p  = pn;
  }
}

__global__ __launch_bounds__(256) void wkv_phase3(
    const unsigned short* __restrict__ kb, const unsigned short* __restrict__ vb,
    const unsigned short* __restrict__ srb,
    const float* __restrict__ decay, const float* __restrict__ first,
    const float* __restrict__ sa, const float* __restrict__ sb,
    const float* __restrict__ sp,
    unsigned short* __restrict__ zp)
{
  int gid = blockIdx.x*256 + threadIdx.x;       // [0, NCH*B_N*C_N/4)
  int jq = gid % (C_N/4);
  int cb = gid / (C_N/4);
  int b = cb % B_N, c = cb / B_N;
  int j = jq*4;
  f32x4 dv = *(const f32x4*)(decay + j);
  f32x4 fv = *(const f32x4*)(first + j);
  float w[4], uu[4];
  #pragma unroll
  for (int e=0;e<4;++e){
    w[e]  = -__expf(dv[e] * (1.0f/T_N));
    uu[e] = fv[e] * (1.0f/T_N);
  }
  size_t sg = (size_t)cb*C_N + j;
  f32x4 a   = *(const f32x4*)(sa + sg);
  f32x4 bbv = *(const f32x4*)(sb + sg);
  f32x4 p   = *(const f32x4*)(sp + sg);
  size_t base = ((size_t)b*T_N + c*LCH)*C_N + j;
  #pragma unroll 2
  for (int t = 0; t < LCH; ++t){
    size_t o = base + (size_t)t*C_N;
    u16x4 k4 = *(const u16x4*)(kb + o);
    u16x4 v4 = *(const u16x4*)(vb + o);
    u16x4 s4 = *(const u16x4*)(srb + o);
    u16x4 z4;
    #pragma unroll
    for (int e=0;e<4;++e){
      float kt = bf2f(k4[e]), vt = bf2f(v4[e]);
      float uk = uu[e] + kt;
      float qq = fmaxf(p[e], uk);
      float e1 = __expf(p[e] - qq), e2 = __expf(uk - qq);
      float y  = __fdividef(e1*a[e] + e2*vt, e1*bbv[e] + e2);
      z4[e] = f2bf(bf2f(s4[e]) * y);
      float pw = p[e] + w[e];
      float q2 = fmaxf(pw, kt);
      float e1b = __expf(pw - q2), e2b = __expf(kt - q2);
      a[e]   = e1b*a[e]   + e2b*vt;
      bbv[e] = e1b*bbv[e] + e2b;
      p[e]   = q2;
    }
    *(u16x4*)(zp + o) = z4;
  }
}

// ---------------------------------------------------------------------------
extern "C" void kernel_launch(void* const* d_in, const int* in_sizes, int n_in,
                              void* d_out, int out_size, void* d_ws, size_t ws_size,
                              hipStream_t stream)
{
  const float* x     = (const float*)d_in[0];
  const float* Wk    = (const float*)d_in[1];
  const float* Wv    = (const float*)d_in[2];
  const float* Wr    = (const float*)d_in[3];
  const float* Wo    = (const float*)d_in[4];
  const float* decay = (const float*)d_in[5];
  const float* first = (const float*)d_in[6];
  const float* mk    = (const float*)d_in[7];
  const float* mv    = (const float*)d_in[8];
  const float* mr    = (const float*)d_in[9];
  const int*   perm  = (const int*)d_in[10];
  float* out = (float*)d_out;

  char* ws = (char*)d_ws;
  size_t off = 0;
  auto alloc = [&](size_t bytes)->char* {
    char* p = ws + off;
    off += (bytes + 255) & ~(size_t)255;
    return p;
  };
  const size_t MC = (size_t)M_N * C_N;       // 6291456
  const size_t CC = (size_t)C_N * C_N;       // 589824
  const size_t SC = (size_t)NCH * B_N * C_N; // 196608
  unsigned short* xk   = (unsigned short*)alloc(MC*2);
  unsigned short* xv   = (unsigned short*)alloc(MC*2);
  unsigned short* xr   = (unsigned short*)alloc(MC*2);
  unsigned short* zp   = (unsigned short*)alloc(MC*2);
  unsigned short* Wall = (unsigned short*)alloc(CC*3*2);  // k,v,r contiguous
  unsigned short* Wop  = (unsigned short*)alloc(CC*2);
  unsigned short* srb  = (unsigned short*)alloc(MC*2);
  unsigned short* kb   = (unsigned short*)alloc(MC*2);
  unsigned short* vb   = (unsigned short*)alloc(MC*2);
  float* sa  = (float*)alloc(SC*4);
  float* sb  = (float*)alloc(SC*4);
  float* sp  = (float*)alloc(SC*4);

  prep_mix<<<dim3(2304 + 6144), dim3(256), 0, stream>>>(
      x, Wk, Wv, Wr, Wo, perm, mk, mv, mr, Wall, Wop, xk, xv, xr);
  gemm_kvr<<<dim3(M_N/128, 3*C_N/128), dim3(256), 0, stream>>>(
      xk, xv, xr, Wall, kb, vb, srb);
  wkv_phase1<<<dim3(SC/4/256), dim3(256), 0, stream>>>(kb, vb, decay, sa, sb, sp);
  wkv_phase2<<<dim3(B_N*C_N/256), dim3(256), 0, stream>>>(decay, sa, sb, sp);
  wkv_phase3<<<dim3(SC/4/256), dim3(256), 0, stream>>>(kb, vb, srb, decay, first,
                                                       sa, sb, sp, zp);
  gemm_out<<<dim3(M_N/128, C_N/128), dim3(256), 0, stream>>>(zp, Wop, out);
}

// Round 13
// 119.260 us; speedup vs baseline: 1.9175x; 1.9175x over previous
//
#include <hip/hip_runtime.h>
#include <hip/hip_bf16.h>
#include <stdint.h>

#define B_N 8
#define T_N 1024
#define C_N 768
#define M_N (B_N*T_N)   // 8192
#define NCH 32          // chunks along T
#define LCH (T_N/NCH)   // 32
#define BK32 32
#define KS  (C_N/BK32)  // 24 K-steps

typedef __attribute__((ext_vector_type(4))) float f32x4;
typedef __attribute__((ext_vector_type(8))) short s16x8;
typedef __attribute__((ext_vector_type(4))) unsigned short u16x4;

__device__ __forceinline__ unsigned short f2bf(float f){
  unsigned int u = __float_as_uint(f);
  u += 0x7FFFu + ((u >> 16) & 1u);   // round-to-nearest-even
  return (unsigned short)(u >> 16);
}
__device__ __forceinline__ float bf2f(unsigned short h){
  return __uint_as_float(((unsigned int)h) << 16);
}

// async 16B global -> LDS (wave-uniform LDS base + lane*16, per-lane global src)
__device__ __forceinline__ void async16(const unsigned short* g, unsigned short* l){
  __builtin_amdgcn_global_load_lds(
      (const __attribute__((address_space(1))) unsigned int*)g,
      (__attribute__((address_space(3))) unsigned int*)l, 16, 0, 0);
}

// ---------------------------------------------------------------------------
// Fused weight-prep + mix (one launch). Blocks [0,2304): weight prep;
// blocks [2304, 2304+6144): q_shift+mix.
// ---------------------------------------------------------------------------
__global__ __launch_bounds__(256) void prep_mix(
    const float* __restrict__ x,
    const float* __restrict__ Wk, const float* __restrict__ Wv,
    const float* __restrict__ Wr, const float* __restrict__ Wo,
    const int* __restrict__ perm,
    const float* __restrict__ mk, const float* __restrict__ mv, const float* __restrict__ mr,
    unsigned short* __restrict__ Wall, unsigned short* __restrict__ Wop,
    unsigned short* __restrict__ xk, unsigned short* __restrict__ xv,
    unsigned short* __restrict__ xr)
{
  if (blockIdx.x < 2304){
    int idx = blockIdx.x*256 + threadIdx.x;   // [0, C_N*C_N)
    int r = idx / C_N, c = idx - r*C_N;
    int pr = perm[r];
    Wall[idx]                     = f2bf(Wk[pr*C_N + c]);
    Wall[idx +   (size_t)C_N*C_N] = f2bf(Wv[pr*C_N + c]);
    Wall[idx + 2*(size_t)C_N*C_N] = f2bf(Wr[pr*C_N + c]);
    Wop[idx] = f2bf(Wo[r*C_N + perm[c]]);
    return;
  }
  int idx = (blockIdx.x - 2304)*256 + threadIdx.x;   // [0, M_N*C_N/4)
  int n  = idx / (C_N/4);
  int c4 = (idx - n*(C_N/4)) * 4;
  int t = n & (T_N-1);
  int h = t >> 5, w = t & 31;
  int grp = c4 / 192;
  int dh = (grp==2) ? -1 : (grp==3) ? 1 : 0;
  int dw = (grp==0) ? -1 : (grp==1) ? 1 : 0;
  int h2 = h + dh, w2 = w + dw;
  bool valid = ((unsigned)h2 < 32u) && ((unsigned)w2 < 32u);
  f32x4 xc = *(const f32x4*)(x + (size_t)n*C_N + c4);
  f32x4 xx = {0.f,0.f,0.f,0.f};
  if (valid) xx = *(const f32x4*)(x + (size_t)(n + dh*32 + dw)*C_N + c4);
  f32x4 vk = *(const f32x4*)(mk + c4);
  f32x4 vv = *(const f32x4*)(mv + c4);
  f32x4 vr = *(const f32x4*)(mr + c4);
  u16x4 ok, ov, orr;
  #pragma unroll
  for (int i=0;i<4;++i){
    float d = xc[i] - xx[i];
    ok[i]  = f2bf(xx[i] + vk[i]*d);
    ov[i]  = f2bf(xx[i] + vv[i]*d);
    orr[i] = f2bf(xx[i] + vr[i]*d);
  }
  *(u16x4*)(xk + (size_t)n*C_N + c4) = ok;
  *(u16x4*)(xv + (size_t)n*C_N + c4) = ov;
  *(u16x4*)(xr + (size_t)n*C_N + c4) = orr;
}

// ---------------------------------------------------------------------------
// Fused k/v/r GEMM: round-11 verified config. 128x128 tile, 4 waves, BK=32,
// triple-buffered LDS (48 KB, 3 blocks/CU), 2-step counted-vmcnt prefetch,
// T2 granule swizzle, mb-fastest XCD mapping, coalesced bf16 epilogue.
// ---------------------------------------------------------------------------
__global__ __launch_bounds__(256, 3) void gemm_kvr(
    const unsigned short* __restrict__ xk, const unsigned short* __restrict__ xv,
    const unsigned short* __restrict__ xr,
    const unsigned short* __restrict__ Wall,
    unsigned short* __restrict__ kb, unsigned short* __restrict__ vb,
    unsigned short* __restrict__ srb)
{
  // 1152 blocks = 8 XCD chunks x 144; within chunk: mb fastest (8 mb / nb)
  int flat = blockIdx.y * gridDim.x + blockIdx.x;
  const int xcd = flat & 7, q = flat >> 3;       // q in [0,144)
  const int mb = xcd*8 + (q & 7);                // [0,64)
  const int nb = q >> 3;                         // [0,18)
  const int m0 = mb * 128;
  const int n0 = nb * 128;
  const int z  = nb / 6;
  const unsigned short* A = (z==0)? xk : (z==1)? xv : xr;

  __shared__ union {
    struct { unsigned short As[3][128*BK32]; unsigned short Bs[3][128*BK32]; } s;
    unsigned short ct[128*132];                  // padded C-tile for epilogue
  } u;
  const int tid = threadIdx.x;
  const int lane = tid & 63, wid = tid >> 6;
  const int wr = wid >> 1, wc = wid & 1;
  f32x4 acc[4][4];
  #pragma unroll
  for (int i=0;i<4;++i)
    #pragma unroll
    for (int j=0;j<4;++j) acc[i][j] = (f32x4){0.f,0.f,0.f,0.f};

  const int sgcol = ((lane & 3) ^ ((lane >> 3) & 3)) * 8;
  const int srow  = lane >> 2;                 // 0..15
  const int lr  = lane & 15;
  const int kh  = lane >> 4;                   // 0..3
  const int phys = (kh ^ ((lr >> 1) & 3)) * 8; // read-side granule offset (elems)

  auto stage = [&](int buf, int k0){
    #pragma unroll
    for (int i=0;i<2;++i){
      int rbase = i*64 + wid*16;
      async16(&A   [(size_t)(m0 + rbase + srow)*C_N + k0 + sgcol], &u.s.As[buf][rbase*BK32]);
      async16(&Wall[(size_t)(n0 + rbase + srow)*C_N + k0 + sgcol], &u.s.Bs[buf][rbase*BK32]);
    }
  };

  auto compute = [&](int buf){
    s16x8 af[4], bfr[4];
    #pragma unroll
    for (int mi=0;mi<4;++mi) af[mi]  = *(const s16x8*)&u.s.As[buf][(wr*64 + mi*16 + lr)*BK32 + phys];
    #pragma unroll
    for (int ni=0;ni<4;++ni) bfr[ni] = *(const s16x8*)&u.s.Bs[buf][(wc*64 + ni*16 + lr)*BK32 + phys];
    __builtin_amdgcn_s_setprio(1);
    #pragma unroll
    for (int mi=0;mi<4;++mi)
      #pragma unroll
      for (int ni=0;ni<4;++ni)
        acc[mi][ni] = __builtin_amdgcn_mfma_f32_16x16x32_bf16(af[mi], bfr[ni], acc[mi][ni], 0,0,0);
    __builtin_amdgcn_s_setprio(0);
  };

  stage(0, 0);
  stage(1, BK32);
  #pragma unroll 1
  for (int t = 0; t < KS; ++t){
    if (t + 2 < KS) stage((t+2)%3, (t+2)*BK32);   // keep 2-step lead
    if (t + 2 < KS)      asm volatile("s_waitcnt vmcnt(8)" ::: "memory");
    else if (t + 1 < KS) asm volatile("s_waitcnt vmcnt(4)" ::: "memory");
    else                 asm volatile("s_waitcnt vmcnt(0)" ::: "memory");
    __builtin_amdgcn_s_barrier();
    compute(t%3);
    __builtin_amdgcn_s_barrier();
  }

  // ---- coalesced epilogue via padded LDS tile ----
  unsigned short* dst = (z==0)? kb : (z==1)? vb : srb;
  const int colbase = n0 - z*C_N;
  const int lr4 = (lane>>4)*4, lc = lane & 15;
  #pragma unroll
  for (int mi=0;mi<4;++mi){
    #pragma unroll
    for (int ni=0;ni<4;++ni){
      #pragma unroll
      for (int i=0;i<4;++i){
        int r  = wr*64 + mi*16 + lr4 + i;
        int cc = wc*64 + ni*16 + lc;
        float val = acc[mi][ni][i];
        if (z==2) val = 1.f/(1.f + __expf(-val));
        u.ct[r*132 + cc] = f2bf(val);
      }
    }
  }
  __builtin_amdgcn_s_barrier();
  #pragma unroll
  for (int p=0;p<8;++p){
    int f = (p*256 + tid)*8;         // flat elem index in 128x128
    int r = f >> 7, cc = f & 127;
    s16x8 v8 = *(const s16x8*)&u.ct[r*132 + cc];
    *(s16x8*)&dst[(size_t)(m0+r)*C_N + colbase + cc] = v8;
  }
}

// ---------------------------------------------------------------------------
// Final GEMM: out = zp (M x C, bf16) * Wop^T — round-11 config (48 KB tbuf,
// 3 blocks/CU, mb-fastest), direct f32 epilogue (full-line stores).
// ---------------------------------------------------------------------------
__global__ __launch_bounds__(256, 3) void gemm_out(
    const unsigned short* __restrict__ A, const unsigned short* __restrict__ Bw,
    float* __restrict__ out)
{
  // 384 blocks = 8 x 48; mb fastest within chunk
  int flat = blockIdx.y * gridDim.x + blockIdx.x;
  const int xcd = flat & 7, q = flat >> 3;      // q in [0,48)
  const int mb = xcd*8 + (q & 7);               // [0,64)
  const int nb = q >> 3;                        // [0,6)
  const int m0 = mb*128, n0 = nb*128;
  __shared__ __align__(16) unsigned short As[3][128*BK32];
  __shared__ __align__(16) unsigned short Bs[3][128*BK32];
  const int tid = threadIdx.x;
  const int lane = tid & 63, wid = tid >> 6;
  const int wr = wid >> 1, wc = wid & 1;
  f32x4 acc[4][4];
  #pragma unroll
  for (int i=0;i<4;++i)
    #pragma unroll
    for (int j=0;j<4;++j) acc[i][j] = (f32x4){0.f,0.f,0.f,0.f};

  const int sgcol = ((lane & 3) ^ ((lane >> 3) & 3)) * 8;
  const int srow  = lane >> 2;
  const int lr  = lane & 15;
  const int kh  = lane >> 4;
  const int phys = (kh ^ ((lr >> 1) & 3)) * 8;

  auto stage = [&](int buf, int k0){
    #pragma unroll
    for (int i=0;i<2;++i){
      int rbase = i*64 + wid*16;
      async16(&A [(size_t)(m0 + rbase + srow)*C_N + k0 + sgcol], &As[buf][rbase*BK32]);
      async16(&Bw[(size_t)(n0 + rbase + srow)*C_N + k0 + sgcol], &Bs[buf][rbase*BK32]);
    }
  };

  auto compute = [&](int buf){
    s16x8 af[4], bfr[4];
    #pragma unroll
    for (int mi=0;mi<4;++mi) af[mi]  = *(const s16x8*)&As[buf][(wr*64 + mi*16 + lr)*BK32 + phys];
    #pragma unroll
    for (int ni=0;ni<4;++ni) bfr[ni] = *(const s16x8*)&Bs[buf][(wc*64 + ni*16 + lr)*BK32 + phys];
    __builtin_amdgcn_s_setprio(1);
    #pragma unroll
    for (int mi=0;mi<4;++mi)
      #pragma unroll
      for (int ni=0;ni<4;++ni)
        acc[mi][ni] = __builtin_amdgcn_mfma_f32_16x16x32_bf16(af[mi], bfr[ni], acc[mi][ni], 0,0,0);
    __builtin_amdgcn_s_setprio(0);
  };

  stage(0, 0);
  stage(1, BK32);
  #pragma unroll 1
  for (int t = 0; t < KS; ++t){
    if (t + 2 < KS) stage((t+2)%3, (t+2)*BK32);
    if (t + 2 < KS)      asm volatile("s_waitcnt vmcnt(8)" ::: "memory");
    else if (t + 1 < KS) asm volatile("s_waitcnt vmcnt(4)" ::: "memory");
    else                 asm volatile("s_waitcnt vmcnt(0)" ::: "memory");
    __builtin_amdgcn_s_barrier();
    compute(t%3);
    __builtin_amdgcn_s_barrier();
  }

  const int lr4 = (lane>>4)*4, lc = lane & 15;
  #pragma unroll
  for (int mi=0;mi<4;++mi)
    #pragma unroll
    for (int ni=0;ni<4;++ni)
      #pragma unroll
      for (int i=0;i<4;++i){
        int m = m0 + wr*64 + mi*16 + lr4 + i;
        int n = n0 + wc*64 + ni*16 + lc;
        out[(size_t)m*C_N + n] = acc[mi][ni][i];
      }
}

// ---------------------------------------------------------------------------
// WKV chunked scan — x4 vectorized along j (4 independent scan chains/thread).
// ---------------------------------------------------------------------------
__global__ __launch_bounds__(256) void wkv_phase1(
    const unsigned short* __restrict__ kb, const unsigned short* __restrict__ vb,
    const float* __restrict__ decay,
    float* __restrict__ sa, float* __restrict__ sb, float* __restrict__ sp)
{
  int gid = blockIdx.x*256 + threadIdx.x;       // [0, NCH*B_N*C_N/4)
  int jq = gid % (C_N/4);
  int cb = gid / (C_N/4);
  int b = cb % B_N, c = cb / B_N;
  int j = jq*4;
  f32x4 dv = *(const f32x4*)(decay + j);
  float w[4];
  #pragma unroll
  for (int e=0;e<4;++e) w[e] = -__expf(dv[e] * (1.0f/T_N));
  f32x4 a = {0.f,0.f,0.f,0.f}, bbv = {0.f,0.f,0.f,0.f};
  f32x4 p = {-1e38f,-1e38f,-1e38f,-1e38f};
  size_t base = ((size_t)b*T_N + c*LCH)*C_N + j;
  #pragma unroll 2
  for (int t = 0; t < LCH; ++t){
    size_t o = base + (size_t)t*C_N;
    u16x4 k4 = *(const u16x4*)(kb + o);
    u16x4 v4 = *(const u16x4*)(vb + o);
    #pragma unroll
    for (int e=0;e<4;++e){
      float kt = bf2f(k4[e]), vt = bf2f(v4[e]);
      float pw = p[e] + w[e];
      float q2 = fmaxf(pw, kt);
      float e1 = __expf(pw - q2), e2 = __expf(kt - q2);
      a[e]   = e1*a[e]   + e2*vt;
      bbv[e] = e1*bbv[e] + e2;
      p[e]   = q2;
    }
  }
  size_t sg = (size_t)cb*C_N + j;
  *(f32x4*)(sa + sg) = a;
  *(f32x4*)(sb + sg) = bbv;
  *(f32x4*)(sp + sg) = p;
}

__global__ __launch_bounds__(256) void wkv_phase2(
    const float* __restrict__ decay,
    float* __restrict__ sa, float* __restrict__ sb, float* __restrict__ sp)
{
  int g = blockIdx.x*256 + threadIdx.x;   // [0, B_N*C_N)
  int j = g % C_N, b = g / C_N;
  float w = -__expf(decay[j] * (1.0f/T_N));
  float wL = w * (float)LCH;
  float a = 0.f, bb = 0.f, p = -1e38f;
  for (int c = 0; c < NCH; ++c){
    size_t idx = ((size_t)c*B_N + b)*C_N + j;
    float la = sa[idx], lb = sb[idx], lp = sp[idx];
    sa[idx] = a; sb[idx] = bb; sp[idx] = p;   // incoming state for chunk c
    float p1 = p + wL;
    float pn = fmaxf(p1, lp);
    float e1 = __expf(p1 - pn), e2 = __expf(lp - pn);
    a  = e1*a + e2*la;
    bb = e1*bb + e2*lb;
    p  = pn;
  }
}

__global__ __launch_bounds__(256) void wkv_phase3(
    const unsigned short* __restrict__ kb, const unsigned short* __restrict__ vb,
    const unsigned short* __restrict__ srb,
    const float* __restrict__ decay, const float* __restrict__ first,
    const float* __restrict__ sa, const float* __restrict__ sb,
    const float* __restrict__ sp,
    unsigned short* __restrict__ zp)
{
  int gid = blockIdx.x*256 + threadIdx.x;       // [0, NCH*B_N*C_N/4)
  int jq = gid % (C_N/4);
  int cb = gid / (C_N/4);
  int b = cb % B_N, c = cb / B_N;
  int j = jq*4;
  f32x4 dv = *(const f32x4*)(decay + j);
  f32x4 fv = *(const f32x4*)(first + j);
  float w[4], uu[4];
  #pragma unroll
  for (int e=0;e<4;++e){
    w[e]  = -__expf(dv[e] * (1.0f/T_N));
    uu[e] = fv[e] * (1.0f/T_N);
  }
  size_t sg = (size_t)cb*C_N + j;
  f32x4 a   = *(const f32x4*)(sa + sg);
  f32x4 bbv = *(const f32x4*)(sb + sg);
  f32x4 p   = *(const f32x4*)(sp + sg);
  size_t base = ((size_t)b*T_N + c*LCH)*C_N + j;
  #pragma unroll 2
  for (int t = 0; t < LCH; ++t){
    size_t o = base + (size_t)t*C_N;
    u16x4 k4 = *(const u16x4*)(kb + o);
    u16x4 v4 = *(const u16x4*)(vb + o);
    u16x4 s4 = *(const u16x4*)(srb + o);
    u16x4 z4;
    #pragma unroll
    for (int e=0;e<4;++e){
      float kt = bf2f(k4[e]), vt = bf2f(v4[e]);
      float uk = uu[e] + kt;
      float qq = fmaxf(p[e], uk);
      float e1 = __expf(p[e] - qq), e2 = __expf(uk - qq);
      float y  = __fdividef(e1*a[e] + e2*vt, e1*bbv[e] + e2);
      z4[e] = f2bf(bf2f(s4[e]) * y);
      float pw = p[e] + w[e];
      float q2 = fmaxf(pw, kt);
      float e1b = __expf(pw - q2), e2b = __expf(kt - q2);
      a[e]   = e1b*a[e]   + e2b*vt;
      bbv[e] = e1b*bbv[e] + e2b;
      p[e]   = q2;
    }
    *(u16x4*)(zp + o) = z4;
  }
}

// ---------------------------------------------------------------------------
extern "C" void kernel_launch(void* const* d_in, const int* in_sizes, int n_in,
                              void* d_out, int out_size, void* d_ws, size_t ws_size,
                              hipStream_t stream)
{
  const float* x     = (const float*)d_in[0];
  const float* Wk    = (const float*)d_in[1];
  const float* Wv    = (const float*)d_in[2];
  const float* Wr    = (const float*)d_in[3];
  const float* Wo    = (const float*)d_in[4];
  const float* decay = (const float*)d_in[5];
  const float* first = (const float*)d_in[6];
  const float* mk    = (const float*)d_in[7];
  const float* mv    = (const float*)d_in[8];
  const float* mr    = (const float*)d_in[9];
  const int*   perm  = (const int*)d_in[10];
  float* out = (float*)d_out;

  char* ws = (char*)d_ws;
  size_t off = 0;
  auto alloc = [&](size_t bytes)->char* {
    char* p = ws + off;
    off += (bytes + 255) & ~(size_t)255;
    return p;
  };
  const size_t MC = (size_t)M_N * C_N;       // 6291456
  const size_t CC = (size_t)C_N * C_N;       // 589824
  const size_t SC = (size_t)NCH * B_N * C_N; // 196608
  unsigned short* xk   = (unsigned short*)alloc(MC*2);
  unsigned short* xv   = (unsigned short*)alloc(MC*2);
  unsigned short* xr   = (unsigned short*)alloc(MC*2);
  unsigned short* zp   = (unsigned short*)alloc(MC*2);
  unsigned short* Wall = (unsigned short*)alloc(CC*3*2);  // k,v,r contiguous
  unsigned short* Wop  = (unsigned short*)alloc(CC*2);
  unsigned short* srb  = (unsigned short*)alloc(MC*2);
  unsigned short* kb   = (unsigned short*)alloc(MC*2);
  unsigned short* vb   = (unsigned short*)alloc(MC*2);
  float* sa  = (float*)alloc(SC*4);
  float* sb  = (float*)alloc(SC*4);
  float* sp  = (float*)alloc(SC*4);

  prep_mix<<<dim3(2304 + 6144), dim3(256), 0, stream>>>(
      x, Wk, Wv, Wr, Wo, perm, mk, mv, mr, Wall, Wop, xk, xv, xr);
  gemm_kvr<<<dim3(M_N/128, 3*C_N/128), dim3(256), 0, stream>>>(
      xk, xv, xr, Wall, kb, vb, srb);
  wkv_phase1<<<dim3(SC/4/256), dim3(256), 0, stream>>>(kb, vb, decay, sa, sb, sp);
  wkv_phase2<<<dim3(B_N*C_N/256), dim3(256), 0, stream>>>(decay, sa, sb, sp);
  wkv_phase3<<<dim3(SC/4/256), dim3(256), 0, stream>>>(kb, vb, srb, decay, first,
                                                       sa, sb, sp, zp);
  gemm_out<<<dim3(M_N/128, C_N/128), dim3(256), 0, stream>>>(zp, Wop, out);
}

// Round 14
// 113.704 us; speedup vs baseline: 2.0112x; 1.0489x over previous
//
#include <hip/hip_runtime.h>
#include <hip/hip_bf16.h>
#include <stdint.h>

#define B_N 8
#define T_N 1024
#define C_N 768
#define M_N (B_N*T_N)   // 8192
#define NCH 32          // chunks along T
#define LCH (T_N/NCH)   // 32
#define BK32 32
#define KS  (C_N/BK32)  // 24 K-steps

typedef __attribute__((ext_vector_type(4))) float f32x4;
typedef __attribute__((ext_vector_type(8))) short s16x8;
typedef __attribute__((ext_vector_type(4))) unsigned short u16x4;

__device__ __forceinline__ unsigned short f2bf(float f){
  unsigned int u = __float_as_uint(f);
  u += 0x7FFFu + ((u >> 16) & 1u);   // round-to-nearest-even
  return (unsigned short)(u >> 16);
}
__device__ __forceinline__ float bf2f(unsigned short h){
  return __uint_as_float(((unsigned int)h) << 16);
}

// async 16B global -> LDS (wave-uniform LDS base + lane*16, per-lane global src)
__device__ __forceinline__ void async16(const unsigned short* g, unsigned short* l){
  __builtin_amdgcn_global_load_lds(
      (const __attribute__((address_space(1))) unsigned int*)g,
      (__attribute__((address_space(3))) unsigned int*)l, 16, 0, 0);
}

// ---------------------------------------------------------------------------
// Fused weight-prep + mix (one launch). Blocks [0,2304): weight prep;
// blocks [2304, 2304+6144): q_shift+mix.
// ---------------------------------------------------------------------------
__global__ __launch_bounds__(256) void prep_mix(
    const float* __restrict__ x,
    const float* __restrict__ Wk, const float* __restrict__ Wv,
    const float* __restrict__ Wr, const float* __restrict__ Wo,
    const int* __restrict__ perm,
    const float* __restrict__ mk, const float* __restrict__ mv, const float* __restrict__ mr,
    unsigned short* __restrict__ Wall, unsigned short* __restrict__ Wop,
    unsigned short* __restrict__ xk, unsigned short* __restrict__ xv,
    unsigned short* __restrict__ xr)
{
  if (blockIdx.x < 2304){
    int idx = blockIdx.x*256 + threadIdx.x;   // [0, C_N*C_N)
    int r = idx / C_N, c = idx - r*C_N;
    int pr = perm[r];
    Wall[idx]                     = f2bf(Wk[pr*C_N + c]);
    Wall[idx +   (size_t)C_N*C_N] = f2bf(Wv[pr*C_N + c]);
    Wall[idx + 2*(size_t)C_N*C_N] = f2bf(Wr[pr*C_N + c]);
    Wop[idx] = f2bf(Wo[r*C_N + perm[c]]);
    return;
  }
  int idx = (blockIdx.x - 2304)*256 + threadIdx.x;   // [0, M_N*C_N/4)
  int n  = idx / (C_N/4);
  int c4 = (idx - n*(C_N/4)) * 4;
  int t = n & (T_N-1);
  int h = t >> 5, w = t & 31;
  int grp = c4 / 192;
  int dh = (grp==2) ? -1 : (grp==3) ? 1 : 0;
  int dw = (grp==0) ? -1 : (grp==1) ? 1 : 0;
  int h2 = h + dh, w2 = w + dw;
  bool valid = ((unsigned)h2 < 32u) && ((unsigned)w2 < 32u);
  f32x4 xc = *(const f32x4*)(x + (size_t)n*C_N + c4);
  f32x4 xx = {0.f,0.f,0.f,0.f};
  if (valid) xx = *(const f32x4*)(x + (size_t)(n + dh*32 + dw)*C_N + c4);
  f32x4 vk = *(const f32x4*)(mk + c4);
  f32x4 vv = *(const f32x4*)(mv + c4);
  f32x4 vr = *(const f32x4*)(mr + c4);
  u16x4 ok, ov, orr;
  #pragma unroll
  for (int i=0;i<4;++i){
    float d = xc[i] - xx[i];
    ok[i]  = f2bf(xx[i] + vk[i]*d);
    ov[i]  = f2bf(xx[i] + vv[i]*d);
    orr[i] = f2bf(xx[i] + vr[i]*d);
  }
  *(u16x4*)(xk + (size_t)n*C_N + c4) = ok;
  *(u16x4*)(xv + (size_t)n*C_N + c4) = ov;
  *(u16x4*)(xr + (size_t)n*C_N + c4) = orr;
}

// ---------------------------------------------------------------------------
// Fused k/v/r GEMM: 128x128 tile, 4 waves, BK=32, DOUBLE-buffered LDS (32 KB
// union incl. half-tile epilogue) at __launch_bounds__(256,4) -> 4 blocks/CU
// (16 waves/CU TLP; VGPR cap 128 >> 68, no spill). 1-step counted-vmcnt
// prefetch; T2 granule swizzle; mb-fastest XCD mapping; two-pass coalesced
// bf16 epilogue.
// ---------------------------------------------------------------------------
__global__ __launch_bounds__(256, 4) void gemm_kvr(
    const unsigned short* __restrict__ xk, const unsigned short* __restrict__ xv,
    const unsigned short* __restrict__ xr,
    const unsigned short* __restrict__ Wall,
    unsigned short* __restrict__ kb, unsigned short* __restrict__ vb,
    unsigned short* __restrict__ srb)
{
  // 1152 blocks = 8 XCD chunks x 144; within chunk: mb fastest (8 mb / nb)
  int flat = blockIdx.y * gridDim.x + blockIdx.x;
  const int xcd = flat & 7, q = flat >> 3;       // q in [0,144)
  const int mb = xcd*8 + (q & 7);                // [0,64)
  const int nb = q >> 3;                         // [0,18)
  const int m0 = mb * 128;
  const int n0 = nb * 128;
  const int z  = nb / 6;
  const unsigned short* A = (z==0)? xk : (z==1)? xv : xr;

  __shared__ union {
    struct { unsigned short As[2][128*BK32]; unsigned short Bs[2][128*BK32]; } s;
    unsigned short ct[64*132];                   // padded half C-tile (16.9 KB)
  } u;
  const int tid = threadIdx.x;
  const int lane = tid & 63, wid = tid >> 6;
  const int wr = wid >> 1, wc = wid & 1;
  f32x4 acc[4][4];
  #pragma unroll
  for (int i=0;i<4;++i)
    #pragma unroll
    for (int j=0;j<4;++j) acc[i][j] = (f32x4){0.f,0.f,0.f,0.f};

  const int sgcol = ((lane & 3) ^ ((lane >> 3) & 3)) * 8;
  const int srow  = lane >> 2;                 // 0..15
  const int lr  = lane & 15;
  const int kh  = lane >> 4;                   // 0..3
  const int phys = (kh ^ ((lr >> 1) & 3)) * 8; // read-side granule offset (elems)

  auto stage = [&](int buf, int k0){
    #pragma unroll
    for (int i=0;i<2;++i){
      int rbase = i*64 + wid*16;
      async16(&A   [(size_t)(m0 + rbase + srow)*C_N + k0 + sgcol], &u.s.As[buf][rbase*BK32]);
      async16(&Wall[(size_t)(n0 + rbase + srow)*C_N + k0 + sgcol], &u.s.Bs[buf][rbase*BK32]);
    }
  };

  auto compute = [&](int buf){
    s16x8 af[4], bfr[4];
    #pragma unroll
    for (int mi=0;mi<4;++mi) af[mi]  = *(const s16x8*)&u.s.As[buf][(wr*64 + mi*16 + lr)*BK32 + phys];
    #pragma unroll
    for (int ni=0;ni<4;++ni) bfr[ni] = *(const s16x8*)&u.s.Bs[buf][(wc*64 + ni*16 + lr)*BK32 + phys];
    __builtin_amdgcn_s_setprio(1);
    #pragma unroll
    for (int mi=0;mi<4;++mi)
      #pragma unroll
      for (int ni=0;ni<4;++ni)
        acc[mi][ni] = __builtin_amdgcn_mfma_f32_16x16x32_bf16(af[mi], bfr[ni], acc[mi][ni], 0,0,0);
    __builtin_amdgcn_s_setprio(0);
  };

  stage(0, 0);
  #pragma unroll 1
  for (int t = 0; t < KS; ++t){
    if (t + 1 < KS){
      stage((t+1)&1, (t+1)*BK32);                     // next tile in flight
      asm volatile("s_waitcnt vmcnt(4)" ::: "memory"); // tile t landed
    } else {
      asm volatile("s_waitcnt vmcnt(0)" ::: "memory");
    }
    __builtin_amdgcn_s_barrier();
    compute(t & 1);
    __builtin_amdgcn_s_barrier();                      // guard buffer reuse
  }

  // ---- two-pass coalesced epilogue via padded half-tile LDS ----
  unsigned short* dst = (z==0)? kb : (z==1)? vb : srb;
  const int colbase = n0 - z*C_N;
  const int lr4 = (lane>>4)*4, lc = lane & 15;
  #pragma unroll
  for (int p=0;p<2;++p){
    if (p) __builtin_amdgcn_s_barrier();
    if (wr == p){
      #pragma unroll
      for (int mi=0;mi<4;++mi){
        #pragma unroll
        for (int ni=0;ni<4;++ni){
          #pragma unroll
          for (int i=0;i<4;++i){
            int r  = mi*16 + lr4 + i;          // 0..63 local row
            int cc = wc*64 + ni*16 + lc;
            float val = acc[mi][ni][i];
            if (z==2) val = 1.f/(1.f + __expf(-val));
            u.ct[r*132 + cc] = f2bf(val);
          }
        }
      }
    }
    __builtin_amdgcn_s_barrier();
    #pragma unroll
    for (int qq=0;qq<4;++qq){
      int f = (qq*256 + tid)*8;                // flat elem in 64x128
      int r = f >> 7, cc = f & 127;
      s16x8 v8 = *(const s16x8*)&u.ct[r*132 + cc];
      *(s16x8*)&dst[(size_t)(m0 + p*64 + r)*C_N + colbase + cc] = v8;
    }
  }
}

// ---------------------------------------------------------------------------
// Final GEMM: out = zp (M x C, bf16) * Wop^T — same 32 KB dbuf structure,
// (256,4), direct f32 epilogue (full-line stores). 384 blocks all resident.
// ---------------------------------------------------------------------------
__global__ __launch_bounds__(256, 4) void gemm_out(
    const unsigned short* __restrict__ A, const unsigned short* __restrict__ Bw,
    float* __restrict__ out)
{
  // 384 blocks = 8 x 48; mb fastest within chunk
  int flat = blockIdx.y * gridDim.x + blockIdx.x;
  const int xcd = flat & 7, q = flat >> 3;      // q in [0,48)
  const int mb = xcd*8 + (q & 7);               // [0,64)
  const int nb = q >> 3;                        // [0,6)
  const int m0 = mb*128, n0 = nb*128;
  __shared__ __align__(16) unsigned short As[2][128*BK32];
  __shared__ __align__(16) unsigned short Bs[2][128*BK32];
  const int tid = threadIdx.x;
  const int lane = tid & 63, wid = tid >> 6;
  const int wr = wid >> 1, wc = wid & 1;
  f32x4 acc[4][4];
  #pragma unroll
  for (int i=0;i<4;++i)
    #pragma unroll
    for (int j=0;j<4;++j) acc[i][j] = (f32x4){0.f,0.f,0.f,0.f};

  const int sgcol = ((lane & 3) ^ ((lane >> 3) & 3)) * 8;
  const int srow  = lane >> 2;
  const int lr  = lane & 15;
  const int kh  = lane >> 4;
  const int phys = (kh ^ ((lr >> 1) & 3)) * 8;

  auto stage = [&](int buf, int k0){
    #pragma unroll
    for (int i=0;i<2;++i){
      int rbase = i*64 + wid*16;
      async16(&A [(size_t)(m0 + rbase + srow)*C_N + k0 + sgcol], &As[buf][rbase*BK32]);
      async16(&Bw[(size_t)(n0 + rbase + srow)*C_N + k0 + sgcol], &Bs[buf][rbase*BK32]);
    }
  };

  auto compute = [&](int buf){
    s16x8 af[4], bfr[4];
    #pragma unroll
    for (int mi=0;mi<4;++mi) af[mi]  = *(const s16x8*)&As[buf][(wr*64 + mi*16 + lr)*BK32 + phys];
    #pragma unroll
    for (int ni=0;ni<4;++ni) bfr[ni] = *(const s16x8*)&Bs[buf][(wc*64 + ni*16 + lr)*BK32 + phys];
    __builtin_amdgcn_s_setprio(1);
    #pragma unroll
    for (int mi=0;mi<4;++mi)
      #pragma unroll
      for (int ni=0;ni<4;++ni)
        acc[mi][ni] = __builtin_amdgcn_mfma_f32_16x16x32_bf16(af[mi], bfr[ni], acc[mi][ni], 0,0,0);
    __builtin_amdgcn_s_setprio(0);
  };

  stage(0, 0);
  #pragma unroll 1
  for (int t = 0; t < KS; ++t){
    if (t + 1 < KS){
      stage((t+1)&1, (t+1)*BK32);
      asm volatile("s_waitcnt vmcnt(4)" ::: "memory");
    } else {
      asm volatile("s_waitcnt vmcnt(0)" ::: "memory");
    }
    __builtin_amdgcn_s_barrier();
    compute(t & 1);
    __builtin_amdgcn_s_barrier();
  }

  const int lr4 = (lane>>4)*4, lc = lane & 15;
  #pragma unroll
  for (int mi=0;mi<4;++mi)
    #pragma unroll
    for (int ni=0;ni<4;++ni)
      #pragma unroll
      for (int i=0;i<4;++i){
        int m = m0 + wr*64 + mi*16 + lr4 + i;
        int n = n0 + wc*64 + ni*16 + lc;
        out[(size_t)m*C_N + n] = acc[mi][ni][i];
      }
}

// ---------------------------------------------------------------------------
// WKV chunked scan — scalar per-j (round-11 proven: 12 waves/CU TLP beats
// 4-wide ILP at 3 waves/CU for this latency-chain). k/v/sr are bf16.
// ---------------------------------------------------------------------------
__global__ __launch_bounds__(256) void wkv_phase1(
    const unsigned short* __restrict__ kb, const unsigned short* __restrict__ vb,
    const float* __restrict__ decay,
    float* __restrict__ sa, float* __restrict__ sb, float* __restrict__ sp)
{
  int g = blockIdx.x*256 + threadIdx.x;   // [0, NCH*B_N*C_N)
  int j = g % C_N;
  int cb = g / C_N;
  int b = cb % B_N, c = cb / B_N;
  float w = -__expf(decay[j] * (1.0f/T_N));
  float a = 0.f, bb = 0.f, p = -1e38f;
  size_t base = ((size_t)b*T_N + c*LCH)*C_N + j;
  #pragma unroll 4
  for (int t = 0; t < LCH; ++t){
    size_t o = base + (size_t)t*C_N;
    float kt = bf2f(kb[o]), vt = bf2f(vb[o]);
    float pw = p + w;
    float q2 = fmaxf(pw, kt);
    float e1 = __expf(pw - q2), e2 = __expf(kt - q2);
    a  = e1*a + e2*vt;
    bb = e1*bb + e2;
    p  = q2;
  }
  sa[g] = a; sb[g] = bb; sp[g] = p;
}

__global__ __launch_bounds__(256) void wkv_phase2(
    const float* __restrict__ decay,
    float* __restrict__ sa, float* __restrict__ sb, float* __restrict__ sp)
{
  int g = blockIdx.x*256 + threadIdx.x;   // [0, B_N*C_N)
  int j = g % C_N, b = g / C_N;
  float w = -__expf(decay[j] * (1.0f/T_N));
  float wL = w * (float)LCH;
  float a = 0.f, bb = 0.f, p = -1e38f;
  for (int c = 0; c < NCH; ++c){
    size_t idx = ((size_t)c*B_N + b)*C_N + j;
    float la = sa[idx], lb = sb[idx], lp = sp[idx];
    sa[idx] = a; sb[idx] = bb; sp[idx] = p;   // incoming state for chunk c
    float p1 = p + wL;
    float pn = fmaxf(p1, lp);
    float e1 = __expf(p1 - pn), e2 = __expf(lp - pn);
    a  = e1*a + e2*la;
    bb = e1*bb + e2*lb;
    p  = pn;
  }
}

__global__ __launch_bounds__(256) void wkv_phase3(
    const unsigned short* __restrict__ kb, const unsigned short* __restrict__ vb,
    const unsigned short* __restrict__ srb,
    const float* __restrict__ decay, const float* __restrict__ first,
    const float* __restrict__ sa, const float* __restrict__ sb,
    const float* __restrict__ sp,
    unsigned short* __restrict__ zp)
{
  int g = blockIdx.x*256 + threadIdx.x;   // [0, NCH*B_N*C_N)
  int j = g % C_N;
  int cb = g / C_N;
  int b = cb % B_N, c = cb / B_N;
  float w = -__expf(decay[j] * (1.0f/T_N));
  float u = first[j] * (1.0f/T_N);
  float a = sa[g], bb = sb[g], p = sp[g];
  size_t base = ((size_t)b*T_N + c*LCH)*C_N + j;
  #pragma unroll 2
  for (int t = 0; t < LCH; ++t){
    size_t o = base + (size_t)t*C_N;
    float kt = bf2f(kb[o]), vt = bf2f(vb[o]);
    float uk = u + kt;
    float q  = fmaxf(p, uk);
    float e1 = __expf(p - q), e2 = __expf(uk - q);
    float y  = __fdividef(e1*a + e2*vt, e1*bb + e2);
    zp[o] = f2bf(bf2f(srb[o]) * y);
    float pw = p + w;
    float q2 = fmaxf(pw, kt);
    float e1b = __expf(pw - q2), e2b = __expf(kt - q2);
    a  = e1b*a + e2b*vt;
    bb = e1b*bb + e2b;
    p  = q2;
  }
}

// ---------------------------------------------------------------------------
extern "C" void kernel_launch(void* const* d_in, const int* in_sizes, int n_in,
                              void* d_out, int out_size, void* d_ws, size_t ws_size,
                              hipStream_t stream)
{
  const float* x     = (const float*)d_in[0];
  const float* Wk    = (const float*)d_in[1];
  const float* Wv    = (const float*)d_in[2];
  const float* Wr    = (const float*)d_in[3];
  const float* Wo    = (const float*)d_in[4];
  const float* decay = (const float*)d_in[5];
  const float* first = (const float*)d_in[6];
  const float* mk    = (const float*)d_in[7];
  const float* mv    = (const float*)d_in[8];
  const float* mr    = (const float*)d_in[9];
  const int*   perm  = (const int*)d_in[10];
  float* out = (float*)d_out;

  char* ws = (char*)d_ws;
  size_t off = 0;
  auto alloc = [&](size_t bytes)->char* {
    char* p = ws + off;
    off += (bytes + 255) & ~(size_t)255;
    return p;
  };
  const size_t MC = (size_t)M_N * C_N;       // 6291456
  const size_t CC = (size_t)C_N * C_N;       // 589824
  const size_t SC = (size_t)NCH * B_N * C_N; // 196608
  unsigned short* xk   = (unsigned short*)alloc(MC*2);
  unsigned short* xv   = (unsigned short*)alloc(MC*2);
  unsigned short* xr   = (unsigned short*)alloc(MC*2);
  unsigned short* zp   = (unsigned short*)alloc(MC*2);
  unsigned short* Wall = (unsigned short*)alloc(CC*3*2);  // k,v,r contiguous
  unsigned short* Wop  = (unsigned short*)alloc(CC*2);
  unsigned short* srb  = (unsigned short*)alloc(MC*2);
  unsigned short* kb   = (unsigned short*)alloc(MC*2);
  unsigned short* vb   = (unsigned short*)alloc(MC*2);
  float* sa  = (float*)alloc(SC*4);
  float* sb  = (float*)alloc(SC*4);
  float* sp  = (float*)alloc(SC*4);

  prep_mix<<<dim3(2304 + 6144), dim3(256), 0, stream>>>(
      x, Wk, Wv, Wr, Wo, perm, mk, mv, mr, Wall, Wop, xk, xv, xr);
  gemm_kvr<<<dim3(M_N/128, 3*C_N/128), dim3(256), 0, stream>>>(
      xk, xv, xr, Wall, kb, vb, srb);
  wkv_phase1<<<dim3(SC/256), dim3(256), 0, stream>>>(kb, vb, decay, sa, sb, sp);
  wkv_phase2<<<dim3(B_N*C_N/256), dim3(256), 0, stream>>>(decay, sa, sb, sp);
  wkv_phase3<<<dim3(SC/256), dim3(256), 0, stream>>>(kb, vb, srb, decay, first,
                                                     sa, sb, sp, zp);
  gemm_out<<<dim3(M_N/128, C_N/128), dim3(256), 0, stream>>>(zp, Wop, out);
}

// Round 15
// 108.758 us; speedup vs baseline: 2.1026x; 1.0455x over previous
//
#include <hip/hip_runtime.h>
#include <hip/hip_bf16.h>
#include <stdint.h>

#define B_N 8
#define T_N 1024
#define C_N 768
#define M_N (B_N*T_N)   // 8192
#define NCH 32          // chunks along T
#define LCH (T_N/NCH)   // 32
#define BK32 32
#define KS  (C_N/BK32)  // 24 K-steps

typedef __attribute__((ext_vector_type(4))) float f32x4;
typedef __attribute__((ext_vector_type(8))) short s16x8;
typedef __attribute__((ext_vector_type(4))) unsigned short u16x4;

__device__ __forceinline__ unsigned short f2bf(float f){
  unsigned int u = __float_as_uint(f);
  u += 0x7FFFu + ((u >> 16) & 1u);   // round-to-nearest-even
  return (unsigned short)(u >> 16);
}
__device__ __forceinline__ float bf2f(unsigned short h){
  return __uint_as_float(((unsigned int)h) << 16);
}

// async 16B global -> LDS (wave-uniform LDS base + lane*16, per-lane global src)
__device__ __forceinline__ void async16(const unsigned short* g, unsigned short* l){
  __builtin_amdgcn_global_load_lds(
      (const __attribute__((address_space(1))) unsigned int*)g,
      (__attribute__((address_space(3))) unsigned int*)l, 16, 0, 0);
}

// ---------------------------------------------------------------------------
// Fused weight-prep + mix (one launch). Blocks [0,2304): weight prep;
// blocks [2304, 2304+6144): q_shift+mix.
// ---------------------------------------------------------------------------
__global__ __launch_bounds__(256) void prep_mix(
    const float* __restrict__ x,
    const float* __restrict__ Wk, const float* __restrict__ Wv,
    const float* __restrict__ Wr, const float* __restrict__ Wo,
    const int* __restrict__ perm,
    const float* __restrict__ mk, const float* __restrict__ mv, const float* __restrict__ mr,
    unsigned short* __restrict__ Wall, unsigned short* __restrict__ Wop,
    unsigned short* __restrict__ xk, unsigned short* __restrict__ xv,
    unsigned short* __restrict__ xr)
{
  if (blockIdx.x < 2304){
    int idx = blockIdx.x*256 + threadIdx.x;   // [0, C_N*C_N)
    int r = idx / C_N, c = idx - r*C_N;
    int pr = perm[r];
    Wall[idx]                     = f2bf(Wk[pr*C_N + c]);
    Wall[idx +   (size_t)C_N*C_N] = f2bf(Wv[pr*C_N + c]);
    Wall[idx + 2*(size_t)C_N*C_N] = f2bf(Wr[pr*C_N + c]);
    Wop[idx] = f2bf(Wo[r*C_N + perm[c]]);
    return;
  }
  int idx = (blockIdx.x - 2304)*256 + threadIdx.x;   // [0, M_N*C_N/4)
  int n  = idx / (C_N/4);
  int c4 = (idx - n*(C_N/4)) * 4;
  int t = n & (T_N-1);
  int h = t >> 5, w = t & 31;
  int grp = c4 / 192;
  int dh = (grp==2) ? -1 : (grp==3) ? 1 : 0;
  int dw = (grp==0) ? -1 : (grp==1) ? 1 : 0;
  int h2 = h + dh, w2 = w + dw;
  bool valid = ((unsigned)h2 < 32u) && ((unsigned)w2 < 32u);
  f32x4 xc = *(const f32x4*)(x + (size_t)n*C_N + c4);
  f32x4 xx = {0.f,0.f,0.f,0.f};
  if (valid) xx = *(const f32x4*)(x + (size_t)(n + dh*32 + dw)*C_N + c4);
  f32x4 vk = *(const f32x4*)(mk + c4);
  f32x4 vv = *(const f32x4*)(mv + c4);
  f32x4 vr = *(const f32x4*)(mr + c4);
  u16x4 ok, ov, orr;
  #pragma unroll
  for (int i=0;i<4;++i){
    float d = xc[i] - xx[i];
    ok[i]  = f2bf(xx[i] + vk[i]*d);
    ov[i]  = f2bf(xx[i] + vv[i]*d);
    orr[i] = f2bf(xx[i] + vr[i]*d);
  }
  *(u16x4*)(xk + (size_t)n*C_N + c4) = ok;
  *(u16x4*)(xv + (size_t)n*C_N + c4) = ov;
  *(u16x4*)(xr + (size_t)n*C_N + c4) = orr;
}

// ---------------------------------------------------------------------------
// Fused k/v/r GEMM: 128x192 tile, 4 waves (2x2, per-wave 64x96, acc[4][6]).
// Grid = 64 mb x 12 nb = 768 blocks = EXACTLY 3 blocks/CU (LDS padded to
// 48 KB) -> perfectly balanced single scheduling round. BK=32 double-buffer,
// 1-step counted vmcnt(5) lead (5 stage instrs/wave), T2 granule swizzle,
// mb-fastest XCD mapping, two-pass coalesced bf16 epilogue.
// ---------------------------------------------------------------------------
__global__ __launch_bounds__(256, 3) void gemm_kvr(
    const unsigned short* __restrict__ xk, const unsigned short* __restrict__ xv,
    const unsigned short* __restrict__ xr,
    const unsigned short* __restrict__ Wall,
    unsigned short* __restrict__ kb, unsigned short* __restrict__ vb,
    unsigned short* __restrict__ srb)
{
  // 768 blocks = 8 XCD chunks x 96; within chunk: mb fastest (8 mb / nb)
  int flat = blockIdx.x;
  const int xcd = flat & 7, q = flat >> 3;       // q in [0,96)
  const int mb = xcd*8 + (q & 7);                // [0,64)
  const int nb = q >> 3;                         // [0,12)
  const int m0 = mb * 128;
  const int n0 = nb * 192;
  const int z  = nb >> 2;                        // 4 nb per 768 cols
  const unsigned short* A = (z==0)? xk : (z==1)? xv : xr;

  __shared__ union {
    struct {
      unsigned short As[2][128*BK32];            // 16 KB
      unsigned short Bs[2][192*BK32];            // 24 KB
      unsigned short pad[4096];                  // -> 48 KB total (3 blocks/CU)
    } s;
    unsigned short ct[64*200];                   // padded half C-tile (25.0 KB)
  } u;
  const int tid = threadIdx.x;
  const int lane = tid & 63, wid = tid >> 6;
  const int wr = wid >> 1, wc = wid & 1;         // 2M x 2N (64 x 96 per wave)
  f32x4 acc[4][6];
  #pragma unroll
  for (int i=0;i<4;++i)
    #pragma unroll
    for (int j=0;j<6;++j) acc[i][j] = (f32x4){0.f,0.f,0.f,0.f};

  const int sgcol = ((lane & 3) ^ ((lane >> 3) & 3)) * 8;
  const int srow  = lane >> 2;                 // 0..15
  const int lr  = lane & 15;
  const int kh  = lane >> 4;                   // 0..3
  const int phys = (kh ^ ((lr >> 1) & 3)) * 8; // read-side granule offset (elems)

  auto stage = [&](int buf, int k0){
    #pragma unroll
    for (int i=0;i<2;++i){                     // A: 128 rows, 2 instr/wave
      int rbase = i*64 + wid*16;
      async16(&A[(size_t)(m0 + rbase + srow)*C_N + k0 + sgcol], &u.s.As[buf][rbase*BK32]);
    }
    #pragma unroll
    for (int i=0;i<3;++i){                     // B: 192 rows, 3 instr/wave
      int rbase = i*64 + wid*16;
      async16(&Wall[(size_t)(n0 + rbase + srow)*C_N + k0 + sgcol], &u.s.Bs[buf][rbase*BK32]);
    }
  };

  auto compute = [&](int buf){
    s16x8 af[4], bfr[6];
    #pragma unroll
    for (int mi=0;mi<4;++mi) af[mi]  = *(const s16x8*)&u.s.As[buf][(wr*64 + mi*16 + lr)*BK32 + phys];
    #pragma unroll
    for (int ni=0;ni<6;++ni) bfr[ni] = *(const s16x8*)&u.s.Bs[buf][(wc*96 + ni*16 + lr)*BK32 + phys];
    __builtin_amdgcn_s_setprio(1);
    #pragma unroll
    for (int mi=0;mi<4;++mi)
      #pragma unroll
      for (int ni=0;ni<6;++ni)
        acc[mi][ni] = __builtin_amdgcn_mfma_f32_16x16x32_bf16(af[mi], bfr[ni], acc[mi][ni], 0,0,0);
    __builtin_amdgcn_s_setprio(0);
  };

  stage(0, 0);
  #pragma unroll 1
  for (int t = 0; t < KS; ++t){
    if (t + 1 < KS){
      stage((t+1)&1, (t+1)*BK32);                     // 5 instrs/wave in flight
      asm volatile("s_waitcnt vmcnt(5)" ::: "memory"); // tile t's loads landed
    } else {
      asm volatile("s_waitcnt vmcnt(0)" ::: "memory");
    }
    __builtin_amdgcn_s_barrier();
    compute(t & 1);
    __builtin_amdgcn_s_barrier();                      // guard buffer reuse
  }

  // ---- two-pass coalesced epilogue via padded half-tile LDS ----
  unsigned short* dst = (z==0)? kb : (z==1)? vb : srb;
  const int colbase = n0 - z*C_N;                      // (nb%4)*192
  const int lr4 = (lane>>4)*4, lc = lane & 15;
  #pragma unroll
  for (int p=0;p<2;++p){
    if (p) __builtin_amdgcn_s_barrier();
    if (wr == p){
      #pragma unroll
      for (int mi=0;mi<4;++mi){
        #pragma unroll
        for (int ni=0;ni<6;++ni){
          #pragma unroll
          for (int i=0;i<4;++i){
            int r  = mi*16 + lr4 + i;          // 0..63 local row
            int cc = wc*96 + ni*16 + lc;       // 0..191
            float val = acc[mi][ni][i];
            if (z==2) val = 1.f/(1.f + __expf(-val));
            u.ct[r*200 + cc] = f2bf(val);
          }
        }
      }
    }
    __builtin_amdgcn_s_barrier();
    #pragma unroll
    for (int qq=0;qq<6;++qq){
      int ch = qq*256 + tid;                   // 0..1535 chunks of 8
      int r = ch / 24, cc = (ch - r*24)*8;
      s16x8 v8 = *(const s16x8*)&u.ct[r*200 + cc];
      *(s16x8*)&dst[(size_t)(m0 + p*64 + r)*C_N + colbase + cc] = v8;
    }
  }
}

// ---------------------------------------------------------------------------
// Final GEMM: out = zp (M x C, bf16) * Wop^T — round-11 proven config:
// 128x128, BK=32 triple-buffer (48 KB, 3 blocks/CU), 2-step vmcnt lead,
// mb-fastest mapping, direct f32 epilogue.
// ---------------------------------------------------------------------------
__global__ __launch_bounds__(256, 3) void gemm_out(
    const unsigned short* __restrict__ A, const unsigned short* __restrict__ Bw,
    float* __restrict__ out)
{
  // 384 blocks = 8 x 48; mb fastest within chunk
  int flat = blockIdx.y * gridDim.x + blockIdx.x;
  const int xcd = flat & 7, q = flat >> 3;      // q in [0,48)
  const int mb = xcd*8 + (q & 7);               // [0,64)
  const int nb = q >> 3;                        // [0,6)
  const int m0 = mb*128, n0 = nb*128;
  __shared__ __align__(16) unsigned short As[3][128*BK32];
  __shared__ __align__(16) unsigned short Bs[3][128*BK32];
  const int tid = threadIdx.x;
  const int lane = tid & 63, wid = tid >> 6;
  const int wr = wid >> 1, wc = wid & 1;
  f32x4 acc[4][4];
  #pragma unroll
  for (int i=0;i<4;++i)
    #pragma unroll
    for (int j=0;j<4;++j) acc[i][j] = (f32x4){0.f,0.f,0.f,0.f};

  const int sgcol = ((lane & 3) ^ ((lane >> 3) & 3)) * 8;
  const int srow  = lane >> 2;
  const int lr  = lane & 15;
  const int kh  = lane >> 4;
  const int phys = (kh ^ ((lr >> 1) & 3)) * 8;

  auto stage = [&](int buf, int k0){
    #pragma unroll
    for (int i=0;i<2;++i){
      int rbase = i*64 + wid*16;
      async16(&A [(size_t)(m0 + rbase + srow)*C_N + k0 + sgcol], &As[buf][rbase*BK32]);
      async16(&Bw[(size_t)(n0 + rbase + srow)*C_N + k0 + sgcol], &Bs[buf][rbase*BK32]);
    }
  };

  auto compute = [&](int buf){
    s16x8 af[4], bfr[4];
    #pragma unroll
    for (int mi=0;mi<4;++mi) af[mi]  = *(const s16x8*)&As[buf][(wr*64 + mi*16 + lr)*BK32 + phys];
    #pragma unroll
    for (int ni=0;ni<4;++ni) bfr[ni] = *(const s16x8*)&Bs[buf][(wc*64 + ni*16 + lr)*BK32 + phys];
    __builtin_amdgcn_s_setprio(1);
    #pragma unroll
    for (int mi=0;mi<4;++mi)
      #pragma unroll
      for (int ni=0;ni<4;++ni)
        acc[mi][ni] = __builtin_amdgcn_mfma_f32_16x16x32_bf16(af[mi], bfr[ni], acc[mi][ni], 0,0,0);
    __builtin_amdgcn_s_setprio(0);
  };

  stage(0, 0);
  stage(1, BK32);
  #pragma unroll 1
  for (int t = 0; t < KS; ++t){
    if (t + 2 < KS) stage((t+2)%3, (t+2)*BK32);
    if (t + 2 < KS)      asm volatile("s_waitcnt vmcnt(8)" ::: "memory");
    else if (t + 1 < KS) asm volatile("s_waitcnt vmcnt(4)" ::: "memory");
    else                 asm volatile("s_waitcnt vmcnt(0)" ::: "memory");
    __builtin_amdgcn_s_barrier();
    compute(t%3);
    __builtin_amdgcn_s_barrier();
  }

  const int lr4 = (lane>>4)*4, lc = lane & 15;
  #pragma unroll
  for (int mi=0;mi<4;++mi)
    #pragma unroll
    for (int ni=0;ni<4;++ni)
      #pragma unroll
      for (int i=0;i<4;++i){
        int m = m0 + wr*64 + mi*16 + lr4 + i;
        int n = n0 + wc*64 + ni*16 + lc;
        out[(size_t)m*C_N + n] = acc[mi][ni][i];
      }
}

// ---------------------------------------------------------------------------
// WKV chunked scan — scalar per-j (round-11 proven). k/v/sr are bf16.
// ---------------------------------------------------------------------------
__global__ __launch_bounds__(256) void wkv_phase1(
    const unsigned short* __restrict__ kb, const unsigned short* __restrict__ vb,
    const float* __restrict__ decay,
    float* __restrict__ sa, float* __restrict__ sb, float* __restrict__ sp)
{
  int g = blockIdx.x*256 + threadIdx.x;   // [0, NCH*B_N*C_N)
  int j = g % C_N;
  int cb = g / C_N;
  int b = cb % B_N, c = cb / B_N;
  float w = -__expf(decay[j] * (1.0f/T_N));
  float a = 0.f, bb = 0.f, p = -1e38f;
  size_t base = ((size_t)b*T_N + c*LCH)*C_N + j;
  #pragma unroll 4
  for (int t = 0; t < LCH; ++t){
    size_t o = base + (size_t)t*C_N;
    float kt = bf2f(kb[o]), vt = bf2f(vb[o]);
    float pw = p + w;
    float q2 = fmaxf(pw, kt);
    float e1 = __expf(pw - q2), e2 = __expf(kt - q2);
    a  = e1*a + e2*vt;
    bb = e1*bb + e2;
    p  = q2;
  }
  sa[g] = a; sb[g] = bb; sp[g] = p;
}

__global__ __launch_bounds__(256) void wkv_phase2(
    const float* __restrict__ decay,
    float* __restrict__ sa, float* __restrict__ sb, float* __restrict__ sp)
{
  int g = blockIdx.x*256 + threadIdx.x;   // [0, B_N*C_N)
  int j = g % C_N, b = g / C_N;
  float w = -__expf(decay[j] * (1.0f/T_N));
  float wL = w * (float)LCH;
  float a = 0.f, bb = 0.f, p = -1e38f;
  for (int c = 0; c < NCH; ++c){
    size_t idx = ((size_t)c*B_N + b)*C_N + j;
    float la = sa[idx], lb = sb[idx], lp = sp[idx];
    sa[idx] = a; sb[idx] = bb; sp[idx] = p;   // incoming state for chunk c
    float p1 = p + wL;
    float pn = fmaxf(p1, lp);
    float e1 = __expf(p1 - pn), e2 = __expf(lp - pn);
    a  = e1*a + e2*la;
    bb = e1*bb + e2*lb;
    p  = pn;
  }
}

__global__ __launch_bounds__(256) void wkv_phase3(
    const unsigned short* __restrict__ kb, const unsigned short* __restrict__ vb,
    const unsigned short* __restrict__ srb,
    const float* __restrict__ decay, const float* __restrict__ first,
    const float* __restrict__ sa, const float* __restrict__ sb,
    const float* __restrict__ sp,
    unsigned short* __restrict__ zp)
{
  int g = blockIdx.x*256 + threadIdx.x;   // [0, NCH*B_N*C_N)
  int j = g % C_N;
  int cb = g / C_N;
  int b = cb % B_N, c = cb / B_N;
  float w = -__expf(decay[j] * (1.0f/T_N));
  float u = first[j] * (1.0f/T_N);
  float a = sa[g], bb = sb[g], p = sp[g];
  size_t base = ((size_t)b*T_N + c*LCH)*C_N + j;
  #pragma unroll 2
  for (int t = 0; t < LCH; ++t){
    size_t o = base + (size_t)t*C_N;
    float kt = bf2f(kb[o]), vt = bf2f(vb[o]);
    float uk = u + kt;
    float q  = fmaxf(p, uk);
    float e1 = __expf(p - q), e2 = __expf(uk - q);
    float y  = __fdividef(e1*a + e2*vt, e1*bb + e2);
    zp[o] = f2bf(bf2f(srb[o]) * y);
    float pw = p + w;
    float q2 = fmaxf(pw, kt);
    float e1b = __expf(pw - q2), e2b = __expf(kt - q2);
    a  = e1b*a + e2b*vt;
    bb = e1b*bb + e2b;
    p  = q2;
  }
}

// ---------------------------------------------------------------------------
extern "C" void kernel_launch(void* const* d_in, const int* in_sizes, int n_in,
                              void* d_out, int out_size, void* d_ws, size_t ws_size,
                              hipStream_t stream)
{
  const float* x     = (const float*)d_in[0];
  const float* Wk    = (const float*)d_in[1];
  const float* Wv    = (const float*)d_in[2];
  const float* Wr    = (const float*)d_in[3];
  const float* Wo    = (const float*)d_in[4];
  const float* decay = (const float*)d_in[5];
  const float* first = (const float*)d_in[6];
  const float* mk    = (const float*)d_in[7];
  const float* mv    = (const float*)d_in[8];
  const float* mr    = (const float*)d_in[9];
  const int*   perm  = (const int*)d_in[10];
  float* out = (float*)d_out;

  char* ws = (char*)d_ws;
  size_t off = 0;
  auto alloc = [&](size_t bytes)->char* {
    char* p = ws + off;
    off += (bytes + 255) & ~(size_t)255;
    return p;
  };
  const size_t MC = (size_t)M_N * C_N;       // 6291456
  const size_t CC = (size_t)C_N * C_N;       // 589824
  const size_t SC = (size_t)NCH * B_N * C_N; // 196608
  unsigned short* xk   = (unsigned short*)alloc(MC*2);
  unsigned short* xv   = (unsigned short*)alloc(MC*2);
  unsigned short* xr   = (unsigned short*)alloc(MC*2);
  unsigned short* zp   = (unsigned short*)alloc(MC*2);
  unsigned short* Wall = (unsigned short*)alloc(CC*3*2);  // k,v,r contiguous
  unsigned short* Wop  = (unsigned short*)alloc(CC*2);
  unsigned short* srb  = (unsigned short*)alloc(MC*2);
  unsigned short* kb   = (unsigned short*)alloc(MC*2);
  unsigned short* vb   = (unsigned short*)alloc(MC*2);
  float* sa  = (float*)alloc(SC*4);
  float* sb  = (float*)alloc(SC*4);
  float* sp  = (float*)alloc(SC*4);

  prep_mix<<<dim3(2304 + 6144), dim3(256), 0, stream>>>(
      x, Wk, Wv, Wr, Wo, perm, mk, mv, mr, Wall, Wop, xk, xv, xr);
  gemm_kvr<<<dim3(768), dim3(256), 0, stream>>>(
      xk, xv, xr, Wall, kb, vb, srb);
  wkv_phase1<<<dim3(SC/256), dim3(256), 0, stream>>>(kb, vb, decay, sa, sb, sp);
  wkv_phase2<<<dim3(B_N*C_N/256), dim3(256), 0, stream>>>(decay, sa, sb, sp);
  wkv_phase3<<<dim3(SC/256), dim3(256), 0, stream>>>(kb, vb, srb, decay, first,
                                                     sa, sb, sp, zp);
  gemm_out<<<dim3(M_N/128, C_N/128), dim3(256), 0, stream>>>(zp, Wop, out);
}

// Round 16
// 108.470 us; speedup vs baseline: 2.1082x; 1.0027x over previous
//
#include <hip/hip_runtime.h>
#include <hip/hip_bf16.h>
#include <stdint.h>

#define B_N 8
#define T_N 1024
#define C_N 768
#define M_N (B_N*T_N)   // 8192
#define NCH 32          // chunks along T
#define LCH (T_N/NCH)   // 32
#define BK32 32
#define KS  (C_N/BK32)  // 24 K-steps

typedef __attribute__((ext_vector_type(4))) float f32x4;
typedef __attribute__((ext_vector_type(8))) short s16x8;
typedef __attribute__((ext_vector_type(4))) unsigned short u16x4;

__device__ __forceinline__ unsigned short f2bf(float f){
  unsigned int u = __float_as_uint(f);
  u += 0x7FFFu + ((u >> 16) & 1u);   // round-to-nearest-even
  return (unsigned short)(u >> 16);
}
__device__ __forceinline__ float bf2f(unsigned short h){
  return __uint_as_float(((unsigned int)h) << 16);
}

// async 16B global -> LDS (wave-uniform LDS base + lane*16, per-lane global src)
__device__ __forceinline__ void async16(const unsigned short* g, unsigned short* l){
  __builtin_amdgcn_global_load_lds(
      (const __attribute__((address_space(1))) unsigned int*)g,
      (__attribute__((address_space(3))) unsigned int*)l, 16, 0, 0);
}

// ---------------------------------------------------------------------------
// Fused weight-prep + mix (one launch). Blocks [0,2304): weight prep;
// blocks [2304, 2304+6144): q_shift+mix.
// ---------------------------------------------------------------------------
__global__ __launch_bounds__(256) void prep_mix(
    const float* __restrict__ x,
    const float* __restrict__ Wk, const float* __restrict__ Wv,
    const float* __restrict__ Wr, const float* __restrict__ Wo,
    const int* __restrict__ perm,
    const float* __restrict__ mk, const float* __restrict__ mv, const float* __restrict__ mr,
    unsigned short* __restrict__ Wall, unsigned short* __restrict__ Wop,
    unsigned short* __restrict__ xk, unsigned short* __restrict__ xv,
    unsigned short* __restrict__ xr)
{
  if (blockIdx.x < 2304){
    int idx = blockIdx.x*256 + threadIdx.x;   // [0, C_N*C_N)
    int r = idx / C_N, c = idx - r*C_N;
    int pr = perm[r];
    Wall[idx]                     = f2bf(Wk[pr*C_N + c]);
    Wall[idx +   (size_t)C_N*C_N] = f2bf(Wv[pr*C_N + c]);
    Wall[idx + 2*(size_t)C_N*C_N] = f2bf(Wr[pr*C_N + c]);
    Wop[idx] = f2bf(Wo[r*C_N + perm[c]]);
    return;
  }
  int idx = (blockIdx.x - 2304)*256 + threadIdx.x;   // [0, M_N*C_N/4)
  int n  = idx / (C_N/4);
  int c4 = (idx - n*(C_N/4)) * 4;
  int t = n & (T_N-1);
  int h = t >> 5, w = t & 31;
  int grp = c4 / 192;
  int dh = (grp==2) ? -1 : (grp==3) ? 1 : 0;
  int dw = (grp==0) ? -1 : (grp==1) ? 1 : 0;
  int h2 = h + dh, w2 = w + dw;
  bool valid = ((unsigned)h2 < 32u) && ((unsigned)w2 < 32u);
  f32x4 xc = *(const f32x4*)(x + (size_t)n*C_N + c4);
  f32x4 xx = {0.f,0.f,0.f,0.f};
  if (valid) xx = *(const f32x4*)(x + (size_t)(n + dh*32 + dw)*C_N + c4);
  f32x4 vk = *(const f32x4*)(mk + c4);
  f32x4 vv = *(const f32x4*)(mv + c4);
  f32x4 vr = *(const f32x4*)(mr + c4);
  u16x4 ok, ov, orr;
  #pragma unroll
  for (int i=0;i<4;++i){
    float d = xc[i] - xx[i];
    ok[i]  = f2bf(xx[i] + vk[i]*d);
    ov[i]  = f2bf(xx[i] + vv[i]*d);
    orr[i] = f2bf(xx[i] + vr[i]*d);
  }
  *(u16x4*)(xk + (size_t)n*C_N + c4) = ok;
  *(u16x4*)(xv + (size_t)n*C_N + c4) = ov;
  *(u16x4*)(xr + (size_t)n*C_N + c4) = orr;
}

// ---------------------------------------------------------------------------
// Fused k/v/r GEMM: 128x192 tile, 4 waves (2x2, per-wave 64x96, acc[4][6]).
// Grid = 64 mb x 12 nb = 768 blocks = EXACTLY 3 blocks/CU (48 KB LDS),
// balanced single round. BK=32 double-buffer, 1-step counted vmcnt(5) lead,
// T2 granule swizzle, mb-fastest XCD mapping, two-pass coalesced epilogue.
// (Round-15 verified: 48.1 us.)
// ---------------------------------------------------------------------------
__global__ __launch_bounds__(256, 3) void gemm_kvr(
    const unsigned short* __restrict__ xk, const unsigned short* __restrict__ xv,
    const unsigned short* __restrict__ xr,
    const unsigned short* __restrict__ Wall,
    unsigned short* __restrict__ kb, unsigned short* __restrict__ vb,
    unsigned short* __restrict__ srb)
{
  int flat = blockIdx.x;
  const int xcd = flat & 7, q = flat >> 3;       // q in [0,96)
  const int mb = xcd*8 + (q & 7);                // [0,64)
  const int nb = q >> 3;                         // [0,12)
  const int m0 = mb * 128;
  const int n0 = nb * 192;
  const int z  = nb >> 2;                        // 4 nb per 768 cols
  const unsigned short* A = (z==0)? xk : (z==1)? xv : xr;

  __shared__ union {
    struct {
      unsigned short As[2][128*BK32];            // 16 KB
      unsigned short Bs[2][192*BK32];            // 24 KB
      unsigned short pad[4096];                  // -> 48 KB total (3 blocks/CU)
    } s;
    unsigned short ct[64*200];                   // padded half C-tile (25.0 KB)
  } u;
  const int tid = threadIdx.x;
  const int lane = tid & 63, wid = tid >> 6;
  const int wr = wid >> 1, wc = wid & 1;         // 2M x 2N (64 x 96 per wave)
  f32x4 acc[4][6];
  #pragma unroll
  for (int i=0;i<4;++i)
    #pragma unroll
    for (int j=0;j<6;++j) acc[i][j] = (f32x4){0.f,0.f,0.f,0.f};

  const int sgcol = ((lane & 3) ^ ((lane >> 3) & 3)) * 8;
  const int srow  = lane >> 2;                 // 0..15
  const int lr  = lane & 15;
  const int kh  = lane >> 4;                   // 0..3
  const int phys = (kh ^ ((lr >> 1) & 3)) * 8; // read-side granule offset (elems)

  auto stage = [&](int buf, int k0){
    #pragma unroll
    for (int i=0;i<2;++i){                     // A: 128 rows, 2 instr/wave
      int rbase = i*64 + wid*16;
      async16(&A[(size_t)(m0 + rbase + srow)*C_N + k0 + sgcol], &u.s.As[buf][rbase*BK32]);
    }
    #pragma unroll
    for (int i=0;i<3;++i){                     // B: 192 rows, 3 instr/wave
      int rbase = i*64 + wid*16;
      async16(&Wall[(size_t)(n0 + rbase + srow)*C_N + k0 + sgcol], &u.s.Bs[buf][rbase*BK32]);
    }
  };

  auto compute = [&](int buf){
    s16x8 af[4], bfr[6];
    #pragma unroll
    for (int mi=0;mi<4;++mi) af[mi]  = *(const s16x8*)&u.s.As[buf][(wr*64 + mi*16 + lr)*BK32 + phys];
    #pragma unroll
    for (int ni=0;ni<6;++ni) bfr[ni] = *(const s16x8*)&u.s.Bs[buf][(wc*96 + ni*16 + lr)*BK32 + phys];
    __builtin_amdgcn_s_setprio(1);
    #pragma unroll
    for (int mi=0;mi<4;++mi)
      #pragma unroll
      for (int ni=0;ni<6;++ni)
        acc[mi][ni] = __builtin_amdgcn_mfma_f32_16x16x32_bf16(af[mi], bfr[ni], acc[mi][ni], 0,0,0);
    __builtin_amdgcn_s_setprio(0);
  };

  stage(0, 0);
  #pragma unroll 1
  for (int t = 0; t < KS; ++t){
    if (t + 1 < KS){
      stage((t+1)&1, (t+1)*BK32);                     // 5 instrs/wave in flight
      asm volatile("s_waitcnt vmcnt(5)" ::: "memory"); // tile t's loads landed
    } else {
      asm volatile("s_waitcnt vmcnt(0)" ::: "memory");
    }
    __builtin_amdgcn_s_barrier();
    compute(t & 1);
    __builtin_amdgcn_s_barrier();                      // guard buffer reuse
  }

  // ---- two-pass coalesced epilogue via padded half-tile LDS ----
  unsigned short* dst = (z==0)? kb : (z==1)? vb : srb;
  const int colbase = n0 - z*C_N;                      // (nb%4)*192
  const int lr4 = (lane>>4)*4, lc = lane & 15;
  #pragma unroll
  for (int p=0;p<2;++p){
    if (p) __builtin_amdgcn_s_barrier();
    if (wr == p){
      #pragma unroll
      for (int mi=0;mi<4;++mi){
        #pragma unroll
        for (int ni=0;ni<6;++ni){
          #pragma unroll
          for (int i=0;i<4;++i){
            int r  = mi*16 + lr4 + i;          // 0..63 local row
            int cc = wc*96 + ni*16 + lc;       // 0..191
            float val = acc[mi][ni][i];
            if (z==2) val = 1.f/(1.f + __expf(-val));
            u.ct[r*200 + cc] = f2bf(val);
          }
        }
      }
    }
    __builtin_amdgcn_s_barrier();
    #pragma unroll
    for (int qq=0;qq<6;++qq){
      int ch = qq*256 + tid;                   // 0..1535 chunks of 8
      int r = ch / 24, cc = (ch - r*24)*8;
      s16x8 v8 = *(const s16x8*)&u.ct[r*200 + cc];
      *(s16x8*)&dst[(size_t)(m0 + p*64 + r)*C_N + colbase + cc] = v8;
    }
  }
}

// ---------------------------------------------------------------------------
// Final GEMM: out = zp (M x C, bf16) * Wop^T — 64x128 tile, 4 waves
// (per-wave 32x64, acc[2][4]). Grid = 128 mb x 6 nb = 768 blocks = exactly
// 3 blocks/CU -> balanced single round (fixes the 384-block 75%-util split).
// BK=32 triple-buffer (36.9 KB), 2-step vmcnt lead (3 instr/wave -> 6/3/0),
// mb-fastest mapping, direct f32 epilogue (full 64B lines).
// ---------------------------------------------------------------------------
__global__ __launch_bounds__(256, 3) void gemm_out(
    const unsigned short* __restrict__ A, const unsigned short* __restrict__ Bw,
    float* __restrict__ out)
{
  // 768 blocks = 8 XCD chunks x 96; within chunk: mb fastest (16 mb / nb)
  int flat = blockIdx.x;
  const int xcd = flat & 7, q = flat >> 3;      // q in [0,96)
  const int mb = xcd*16 + (q & 15);             // [0,128)
  const int nb = q >> 4;                        // [0,6)
  const int m0 = mb*64, n0 = nb*128;
  __shared__ __align__(16) unsigned short As[3][64*BK32];    // 12 KB
  __shared__ __align__(16) unsigned short Bs[3][128*BK32];   // 24 KB
  const int tid = threadIdx.x;
  const int lane = tid & 63, wid = tid >> 6;
  const int wr = wid >> 1, wc = wid & 1;        // per-wave 32 x 64
  f32x4 acc[2][4];
  #pragma unroll
  for (int i=0;i<2;++i)
    #pragma unroll
    for (int j=0;j<4;++j) acc[i][j] = (f32x4){0.f,0.f,0.f,0.f};

  const int sgcol = ((lane & 3) ^ ((lane >> 3) & 3)) * 8;
  const int srow  = lane >> 2;                 // 0..15
  const int lr  = lane & 15;
  const int kh  = lane >> 4;
  const int phys = (kh ^ ((lr >> 1) & 3)) * 8;

  auto stage = [&](int buf, int k0){
    // A: 64 rows -> 1 instr/wave
    async16(&A[(size_t)(m0 + wid*16 + srow)*C_N + k0 + sgcol], &As[buf][(wid*16)*BK32]);
    // B: 128 rows -> 2 instr/wave
    #pragma unroll
    for (int i=0;i<2;++i){
      int rbase = i*64 + wid*16;
      async16(&Bw[(size_t)(n0 + rbase + srow)*C_N + k0 + sgcol], &Bs[buf][rbase*BK32]);
    }
  };

  auto compute = [&](int buf){
    s16x8 af[2], bfr[4];
    #pragma unroll
    for (int mi=0;mi<2;++mi) af[mi]  = *(const s16x8*)&As[buf][(wr*32 + mi*16 + lr)*BK32 + phys];
    #pragma unroll
    for (int ni=0;ni<4;++ni) bfr[ni] = *(const s16x8*)&Bs[buf][(wc*64 + ni*16 + lr)*BK32 + phys];
    __builtin_amdgcn_s_setprio(1);
    #pragma unroll
    for (int mi=0;mi<2;++mi)
      #pragma unroll
      for (int ni=0;ni<4;++ni)
        acc[mi][ni] = __builtin_amdgcn_mfma_f32_16x16x32_bf16(af[mi], bfr[ni], acc[mi][ni], 0,0,0);
    __builtin_amdgcn_s_setprio(0);
  };

  stage(0, 0);
  stage(1, BK32);
  #pragma unroll 1
  for (int t = 0; t < KS; ++t){
    if (t + 2 < KS) stage((t+2)%3, (t+2)*BK32);        // keep 2-step lead
    if (t + 2 < KS)      asm volatile("s_waitcnt vmcnt(6)" ::: "memory");
    else if (t + 1 < KS) asm volatile("s_waitcnt vmcnt(3)" ::: "memory");
    else                 asm volatile("s_waitcnt vmcnt(0)" ::: "memory");
    __builtin_amdgcn_s_barrier();
    compute(t%3);
    __builtin_amdgcn_s_barrier();
  }

  const int lr4 = (lane>>4)*4, lc = lane & 15;
  #pragma unroll
  for (int mi=0;mi<2;++mi)
    #pragma unroll
    for (int ni=0;ni<4;++ni)
      #pragma unroll
      for (int i=0;i<4;++i){
        int m = m0 + wr*32 + mi*16 + lr4 + i;
        int n = n0 + wc*64 + ni*16 + lc;
        out[(size_t)m*C_N + n] = acc[mi][ni][i];
      }
}

// ---------------------------------------------------------------------------
// WKV chunked scan — scalar per-j (round-11 proven). k/v/sr are bf16.
// ---------------------------------------------------------------------------
__global__ __launch_bounds__(256) void wkv_phase1(
    const unsigned short* __restrict__ kb, const unsigned short* __restrict__ vb,
    const float* __restrict__ decay,
    float* __restrict__ sa, float* __restrict__ sb, float* __restrict__ sp)
{
  int g = blockIdx.x*256 + threadIdx.x;   // [0, NCH*B_N*C_N)
  int j = g % C_N;
  int cb = g / C_N;
  int b = cb % B_N, c = cb / B_N;
  float w = -__expf(decay[j] * (1.0f/T_N));
  float a = 0.f, bb = 0.f, p = -1e38f;
  size_t base = ((size_t)b*T_N + c*LCH)*C_N + j;
  #pragma unroll 4
  for (int t = 0; t < LCH; ++t){
    size_t o = base + (size_t)t*C_N;
    float kt = bf2f(kb[o]), vt = bf2f(vb[o]);
    float pw = p + w;
    float q2 = fmaxf(pw, kt);
    float e1 = __expf(pw - q2), e2 = __expf(kt - q2);
    a  = e1*a + e2*vt;
    bb = e1*bb + e2;
    p  = q2;
  }
  sa[g] = a; sb[g] = bb; sp[g] = p;
}

__global__ __launch_bounds__(256) void wkv_phase2(
    const float* __restrict__ decay,
    float* __restrict__ sa, float* __restrict__ sb, float* __restrict__ sp)
{
  int g = blockIdx.x*256 + threadIdx.x;   // [0, B_N*C_N)
  int j = g % C_N, b = g / C_N;
  float w = -__expf(decay[j] * (1.0f/T_N));
  float wL = w * (float)LCH;
  float a = 0.f, bb = 0.f, p = -1e38f;
  for (int c = 0; c < NCH; ++c){
    size_t idx = ((size_t)c*B_N + b)*C_N + j;
    float la = sa[idx], lb = sb[idx], lp = sp[idx];
    sa[idx] = a; sb[idx] = bb; sp[idx] = p;   // incoming state for chunk c
    float p1 = p + wL;
    float pn = fmaxf(p1, lp);
    float e1 = __expf(p1 - pn), e2 = __expf(lp - pn);
    a  = e1*a + e2*la;
    bb = e1*bb + e2*lb;
    p  = pn;
  }
}

__global__ __launch_bounds__(256) void wkv_phase3(
    const unsigned short* __restrict__ kb, const unsigned short* __restrict__ vb,
    const unsigned short* __restrict__ srb,
    const float* __restrict__ decay, const float* __restrict__ first,
    const float* __restrict__ sa, const float* __restrict__ sb,
    const float* __restrict__ sp,
    unsigned short* __restrict__ zp)
{
  int g = blockIdx.x*256 + threadIdx.x;   // [0, NCH*B_N*C_N)
  int j = g % C_N;
  int cb = g / C_N;
  int b = cb % B_N, c = cb / B_N;
  float w = -__expf(decay[j] * (1.0f/T_N));
  float u = first[j] * (1.0f/T_N);
  float a = sa[g], bb = sb[g], p = sp[g];
  size_t base = ((size_t)b*T_N + c*LCH)*C_N + j;
  #pragma unroll 2
  for (int t = 0; t < LCH; ++t){
    size_t o = base + (size_t)t*C_N;
    float kt = bf2f(kb[o]), vt = bf2f(vb[o]);
    float uk = u + kt;
    float q  = fmaxf(p, uk);
    float e1 = __expf(p - q), e2 = __expf(uk - q);
    float y  = __fdividef(e1*a + e2*vt, e1*bb + e2);
    zp[o] = f2bf(bf2f(srb[o]) * y);
    float pw = p + w;
    float q2 = fmaxf(pw, kt);
    float e1b = __expf(pw - q2), e2b = __expf(kt - q2);
    a  = e1b*a + e2b*vt;
    bb = e1b*bb + e2b;
    p  = q2;
  }
}

// ---------------------------------------------------------------------------
extern "C" void kernel_launch(void* const* d_in, const int* in_sizes, int n_in,
                              void* d_out, int out_size, void* d_ws, size_t ws_size,
                              hipStream_t stream)
{
  const float* x     = (const float*)d_in[0];
  const float* Wk    = (const float*)d_in[1];
  const float* Wv    = (const float*)d_in[2];
  const float* Wr    = (const float*)d_in[3];
  const float* Wo    = (const float*)d_in[4];
  const float* decay = (const float*)d_in[5];
  const float* first = (const float*)d_in[6];
  const float* mk    = (const float*)d_in[7];
  const float* mv    = (const float*)d_in[8];
  const float* mr    = (const float*)d_in[9];
  const int*   perm  = (const int*)d_in[10];
  float* out = (float*)d_out;

  char* ws = (char*)d_ws;
  size_t off = 0;
  auto alloc = [&](size_t bytes)->char* {
    char* p = ws + off;
    off += (bytes + 255) & ~(size_t)255;
    return p;
  };
  const size_t MC = (size_t)M_N * C_N;       // 6291456
  const size_t CC = (size_t)C_N * C_N;       // 589824
  const size_t SC = (size_t)NCH * B_N * C_N; // 196608
  unsigned short* xk   = (unsigned short*)alloc(MC*2);
  unsigned short* xv   = (unsigned short*)alloc(MC*2);
  unsigned short* xr   = (unsigned short*)alloc(MC*2);
  unsigned short* zp   = (unsigned short*)alloc(MC*2);
  unsigned short* Wall = (unsigned short*)alloc(CC*3*2);  // k,v,r contiguous
  unsigned short* Wop  = (unsigned short*)alloc(CC*2);
  unsigned short* srb  = (unsigned short*)alloc(MC*2);
  unsigned short* kb   = (unsigned short*)alloc(MC*2);
  unsigned short* vb   = (unsigned short*)alloc(MC*2);
  float* sa  = (float*)alloc(SC*4);
  float* sb  = (float*)alloc(SC*4);
  float* sp  = (float*)alloc(SC*4);

  prep_mix<<<dim3(2304 + 6144), dim3(256), 0, stream>>>(
      x, Wk, Wv, Wr, Wo, perm, mk, mv, mr, Wall, Wop, xk, xv, xr);
  gemm_kvr<<<dim3(768), dim3(256), 0, stream>>>(
      xk, xv, xr, Wall, kb, vb, srb);
  wkv_phase1<<<dim3(SC/256), dim3(256), 0, stream>>>(kb, vb, decay, sa, sb, sp);
  wkv_phase2<<<dim3(B_N*C_N/256), dim3(256), 0, stream>>>(decay, sa, sb, sp);
  wkv_phase3<<<dim3(SC/256), dim3(256), 0, stream>>>(kb, vb, srb, decay, first,
                                                     sa, sb, sp, zp);
  gemm_out<<<dim3(768), dim3(256), 0, stream>>>(zp, Wop, out);
}